// Round 6
// baseline (90.559 us; speedup 1.0000x reference)
//
#include <hip/hip_runtime.h>
#include <hip/hip_bf16.h>
#include <math.h>

#define DEV __device__ __forceinline__

typedef __attribute__((ext_vector_type(8))) short short8v;
typedef __attribute__((ext_vector_type(4))) float f32x4;

DEV unsigned short f2bf(float x) {
    unsigned u = __float_as_uint(x);
    return (unsigned short)((u + 0x7fffu + ((u >> 16) & 1u)) >> 16);
}
DEV unsigned pack2(float lo, float hi) {
    return ((unsigned)f2bf(hi) << 16) | (unsigned)f2bf(lo);
}
DEV f32x4 mfma16(short8v a, short8v b, f32x4 c) {
    return __builtin_amdgcn_mfma_f32_16x16x32_bf16(a, b, c, 0, 0, 0);
}

#define NN 2048

struct __align__(16) Smem {
    unsigned short Ubf[128][136];     // 34816 B  staged U slice (bf16)
    int list[2048];                   //  8192 B  compacted neuron ids (dead from top)
    unsigned short hT[32][136];       //  8704 B  LN output, transposed-ish
    union {                           //  8704 B  phase-local scratch
        unsigned short H1[16][264];   //  gelu(hW1+b1)
        unsigned short Bt[32][136];   //  phase-2 B tile
        float T[32][33];              //  phase-0 transpose tile
        unsigned short bounce[16][136]; // phase-1 C2 bounce
    } u;
    int rmapS[128];
    float biasp[32];
    float biasS[32];
    int nidS[32];
    int cnt, deadcnt;
};

// Device-wide barrier: grid must be fully co-resident (256 blocks, 61 KB LDS
// -> >=1 block/CU capacity on all 256 CUs simultaneously). Bounded spin
// (1<<20 iters ~ <=15 ms worst case) so a visibility failure produces a wrong
// answer (detected by harness) rather than a hang.
DEV void gridbar(int* ctr, int nb) {
    __syncthreads();
    if (threadIdx.x == 0) {
        __threadfence();
        __hip_atomic_fetch_add(ctr, 1, __ATOMIC_ACQ_REL, __HIP_MEMORY_SCOPE_AGENT);
        int guard = 0;
        while (guard < (1 << 20)) {
            if (__hip_atomic_load(ctr, __ATOMIC_ACQUIRE, __HIP_MEMORY_SCOPE_AGENT) >= nb)
                break;
            __builtin_amdgcn_s_sleep(2);
            ++guard;
        }
        __threadfence();
    }
    __syncthreads();
}

__global__ __launch_bounds__(256, 1) void fused_kernel(
    const float* __restrict__ U, const int* __restrict__ neuron_regions,
    const int* __restrict__ eids, const int* __restrict__ r_map,
    const float* __restrict__ neuron_slot, const float* __restrict__ region_emb,
    const float* __restrict__ eid_emb, const float* __restrict__ ln_gamma,
    const float* __restrict__ ln_beta, const float* __restrict__ W1,
    const float* __restrict__ b1, const float* __restrict__ W2,
    const float* __restrict__ b2, unsigned short* __restrict__ W1T,
    unsigned short* __restrict__ W2T, float* __restrict__ w2col,
    unsigned short* __restrict__ w_ws, float* __restrict__ bias_ws,
    int* __restrict__ bar, float* __restrict__ out)
{
    __shared__ Smem s;
    const int tid = threadIdx.x;
    const int bid = blockIdx.x;
    const int bb2 = bid >> 6, slot = bid & 63;    // phase-2 identity

    // ---- init LDS scalars ----
    if (tid == 0) { s.cnt = 0; s.deadcnt = 0; }
    if (tid < 32) s.biasp[tid] = 0.f;
    if (tid < 128) s.rmapS[tid] = r_map[tid];

    // ---- stage U[bb2, :, slot, :] -> Ubf (HBM reads issued first) ----
    {
        const int t = tid >> 1, half = tid & 1;
        const float* src = U + ((size_t)((bb2 * 128 + t) * 64 + slot)) * 128 + half * 64;
        unsigned short* dst = &s.Ubf[t][half * 64];
#pragma unroll
        for (int j = 0; j < 16; j++) {
            float4 v = ((const float4*)src)[j];
            ((uint2*)dst)[j] = make_uint2(pack2(v.x, v.y), pack2(v.z, v.w));
        }
    }

    // ---- transpose duty (blocks 0..64) ----
    if (bid < 32) {
        const int tr = bid >> 3, tc = bid & 7;    // W1 [128][256]
#pragma unroll
        for (int p = 0; p < 4; p++) {
            const int i = p * 8 + (tid >> 5), j = tid & 31;
            s.u.T[i][j] = W1[(tr * 32 + i) * 256 + tc * 32 + j];
        }
        __syncthreads();
#pragma unroll
        for (int p = 0; p < 4; p++) {
            const int i = p * 8 + (tid >> 5), j = tid & 31;
            W1T[(tc * 32 + i) * 128 + tr * 32 + j] = f2bf(s.u.T[j][i]);
        }
    } else if (bid < 64) {
        const int bb = bid - 32, tr = bb >> 2, tc = bb & 3;   // W2 [256][129]
#pragma unroll
        for (int p = 0; p < 4; p++) {
            const int i = p * 8 + (tid >> 5), j = tid & 31;
            s.u.T[i][j] = W2[(tr * 32 + i) * 129 + tc * 32 + j];
        }
        __syncthreads();
#pragma unroll
        for (int p = 0; p < 4; p++) {
            const int i = p * 8 + (tid >> 5), j = tid & 31;
            W2T[(tc * 32 + i) * 256 + tr * 32 + j] = f2bf(s.u.T[j][i]);
        }
    } else if (bid == 64) {
        w2col[tid] = W2[tid * 129 + 128];
    }
    __syncthreads();

    // ---- self-compaction: neurons of (bb2, slot); dead from the top (slot 0) ----
    for (int n = tid; n < NN; n += 256) {
        int reg = min(max(neuron_regions[bb2 * NN + n], 0), 127);
        int lrv = s.rmapS[reg];
        if (lrv >= 0) {
            if (min(lrv, 63) == slot) { int p = atomicAdd(&s.cnt, 1); s.list[p] = n; }
        } else if (slot == 0) {
            int p = atomicAdd(&s.deadcnt, 1); s.list[2047 - p] = n;
        }
    }

    // ---- Stage A: e + LayerNorm for 32 hypernet rows -> hT ----
    {
        const int rr = tid >> 4, q = tid & 15;
#pragma unroll
        for (int hh = 0; hh < 2; hh++) {
            const int row = bid * 32 + hh * 16 + rr;
            const int bh = row >> 11, n = row & (NN - 1);
            int nr = min(max(neuron_regions[bh * NN + n], 0), 127);
            int eid = min(max(eids[bh], 0), 255);
            const float* ns = neuron_slot + n * 128 + q * 8;
            const float* re = region_emb + nr * 128 + q * 8;
            const float* ee = eid_emb + eid * 128 + q * 8;
            float e[8];
            {
                float4 a0 = *(const float4*)ns, a1 = *(const float4*)(ns + 4);
                float4 c0 = *(const float4*)re, c1 = *(const float4*)(re + 4);
                float4 d0 = *(const float4*)ee, d1 = *(const float4*)(ee + 4);
                e[0] = a0.x + c0.x + d0.x; e[1] = a0.y + c0.y + d0.y;
                e[2] = a0.z + c0.z + d0.z; e[3] = a0.w + c0.w + d0.w;
                e[4] = a1.x + c1.x + d1.x; e[5] = a1.y + c1.y + d1.y;
                e[6] = a1.z + c1.z + d1.z; e[7] = a1.w + c1.w + d1.w;
            }
            float sm = 0.f, s2 = 0.f;
#pragma unroll
            for (int i = 0; i < 8; i++) { sm += e[i]; s2 += e[i] * e[i]; }
            sm += __shfl_xor(sm, 1); s2 += __shfl_xor(s2, 1);
            sm += __shfl_xor(sm, 2); s2 += __shfl_xor(s2, 2);
            sm += __shfl_xor(sm, 4); s2 += __shfl_xor(s2, 4);
            sm += __shfl_xor(sm, 8); s2 += __shfl_xor(s2, 8);
            const float mu = sm * (1.f / 128.f);
            const float var = s2 * (1.f / 128.f) - mu * mu;
            const float rstd = rsqrtf(var + 1e-5f);
            float4 g0 = *(const float4*)(ln_gamma + q * 8), g1 = *(const float4*)(ln_gamma + q * 8 + 4);
            float4 t0 = *(const float4*)(ln_beta + q * 8),  t1 = *(const float4*)(ln_beta + q * 8 + 4);
            float gm[8] = {g0.x, g0.y, g0.z, g0.w, g1.x, g1.y, g1.z, g1.w};
            float bt[8] = {t0.x, t0.y, t0.z, t0.w, t1.x, t1.y, t1.z, t1.w};
            float h[8];
#pragma unroll
            for (int i = 0; i < 8; i++) h[i] = (e[i] - mu) * rstd * gm[i] + bt[i];
            uint4 pk;
            pk.x = pack2(h[0], h[1]); pk.y = pack2(h[2], h[3]);
            pk.z = pack2(h[4], h[5]); pk.w = pack2(h[6], h[7]);
            *(uint4*)&s.hT[hh * 16 + rr][q * 8] = pk;
        }
    }

    gridbar(bar + 0, 256);    // W1T/W2T/w2col ready

    // ---- Phase 1: hypernet MFMA, 2 halves of 16 rows ----
    const int wv = tid >> 6, l = tid & 63;
    const int lr = l & 15, lh = l >> 4;
    const float b2last = b2[128];

#pragma unroll 1
    for (int half = 0; half < 2; half++) {
        const int row0h = bid * 32 + half * 16;
        short8v afr[4];
#pragma unroll
        for (int ks = 0; ks < 4; ks++)
            afr[ks] = *(const short8v*)&s.hT[half * 16 + lr][ks * 32 + lh * 8];

        f32x4 acc1[4];
        float w2c[4];
#pragma unroll
        for (int nt = 0; nt < 4; nt++) {
            const int n = wv * 64 + nt * 16 + lr;
            short8v bfr[4];
#pragma unroll
            for (int ks = 0; ks < 4; ks++)
                bfr[ks] = *(const short8v*)(W1T + n * 128 + ks * 32 + lh * 8);
            const float bbv = b1[n];
            f32x4 a; a.x = bbv; a.y = bbv; a.z = bbv; a.w = bbv;
#pragma unroll
            for (int ks = 0; ks < 4; ks++) a = mfma16(afr[ks], bfr[ks], a);
            acc1[nt] = a;
            w2c[nt] = w2col[n];
        }

        __syncthreads();   // u-region free (prev half / transpose done)
        float pb[4] = {0.f, 0.f, 0.f, 0.f};
#pragma unroll
        for (int nt = 0; nt < 4; nt++) {
            const int n = wv * 64 + nt * 16 + lr;
#pragma unroll
            for (int j = 0; j < 4; j++) {
                const float x = acc1[nt][j];
                const float g = 0.5f * x * (1.f + erff(x * 0.70710678118654752f));
                s.u.H1[lh * 4 + j][n] = f2bf(g);
                pb[j] += g * w2c[nt];
            }
        }
#pragma unroll
        for (int j = 0; j < 4; j++) {
            pb[j] += __shfl_xor(pb[j], 1);
            pb[j] += __shfl_xor(pb[j], 2);
            pb[j] += __shfl_xor(pb[j], 4);
            pb[j] += __shfl_xor(pb[j], 8);
        }
        if (lr == 0) {
#pragma unroll
            for (int j = 0; j < 4; j++) atomicAdd(&s.biasp[half * 16 + lh * 4 + j], pb[j]);
        }
        __syncthreads();
        if (tid < 16) bias_ws[row0h + tid] = s.biasp[half * 16 + tid] + b2last;

        short8v a2[8];
#pragma unroll
        for (int ks = 0; ks < 8; ks++)
            a2[ks] = *(const short8v*)&s.u.H1[lr][ks * 32 + lh * 8];

        f32x4 acc2[2];
#pragma unroll
        for (int nt = 0; nt < 2; nt++) {
            const int n = wv * 32 + nt * 16 + lr;
            short8v bf[8];
#pragma unroll
            for (int ks = 0; ks < 8; ks++)
                bf[ks] = *(const short8v*)(W2T + n * 256 + ks * 32 + lh * 8);
            const float bbv = b2[n];
            f32x4 a; a.x = bbv; a.y = bbv; a.z = bbv; a.w = bbv;
#pragma unroll
            for (int ks = 0; ks < 8; ks++) a = mfma16(a2[ks], bf[ks], a);
            acc2[nt] = a;
        }

        __syncthreads();   // all a2 reads complete before bounce overwrite
#pragma unroll
        for (int nt = 0; nt < 2; nt++) {
            const int n = wv * 32 + nt * 16 + lr;
#pragma unroll
            for (int j = 0; j < 4; j++)
                s.u.bounce[lh * 4 + j][n] = f2bf(acc2[nt][j]);
        }
        __syncthreads();
        {
            const int r = tid >> 4, c = tid & 15;
            *(uint4*)(w_ws + (size_t)(row0h + r) * 128 + c * 8) = *(const uint4*)&s.u.bounce[r][c * 8];
        }
    }

    gridbar(bar + 1, 256);    // all w_ws / bias_ws ready

    // ---- Phase 2: gather-GEMM for (bb2, slot), scatter-store to out ----
    const int cnt = s.cnt;
    short8v afr2[2][4];
#pragma unroll
    for (int mt = 0; mt < 2; mt++)
#pragma unroll
        for (int ks = 0; ks < 4; ks++)
            afr2[mt][ks] = *(const short8v*)&s.Ubf[wv * 32 + mt * 16 + lr][ks * 32 + lh * 8];

    const int nChunks = (cnt + 31) >> 5;
#pragma unroll 1
    for (int c = 0; c < nChunks; c++) {
        const int base = c * 32;
        const int cc = min(cnt - base, 32);
        __syncthreads();
        if (tid < 32) {
            const int nid = (tid < cc) ? s.list[base + tid] : -1;
            s.nidS[tid] = nid;
            s.biasS[tid] = (nid >= 0) ? bias_ws[bb2 * NN + nid] : 0.f;
        }
        {
            const int jj = tid >> 3, q = tid & 7;
            const int nid = (jj < cc) ? s.list[base + jj] : -1;
            unsigned short* dst = &s.u.Bt[jj][q * 16];
            if (nid >= 0) {
                const uint4* src = (const uint4*)(w_ws + ((size_t)(bb2 * NN + nid)) * 128 + q * 16);
                ((uint4*)dst)[0] = src[0];
                ((uint4*)dst)[1] = src[1];
            } else {
                ((uint4*)dst)[0] = make_uint4(0, 0, 0, 0);
                ((uint4*)dst)[1] = make_uint4(0, 0, 0, 0);
            }
        }
        __syncthreads();

        short8v bfr2[2][4];
#pragma unroll
        for (int nt = 0; nt < 2; nt++)
#pragma unroll
            for (int ks = 0; ks < 4; ks++)
                bfr2[nt][ks] = *(const short8v*)&s.u.Bt[nt * 16 + lr][ks * 32 + lh * 8];

        f32x4 acc[2][2];
#pragma unroll
        for (int mt = 0; mt < 2; mt++)
#pragma unroll
            for (int nt = 0; nt < 2; nt++) {
                acc[mt][nt].x = 0.f; acc[mt][nt].y = 0.f;
                acc[mt][nt].z = 0.f; acc[mt][nt].w = 0.f;
            }
#pragma unroll
        for (int mt = 0; mt < 2; mt++)
#pragma unroll
            for (int nt = 0; nt < 2; nt++)
#pragma unroll
                for (int ks = 0; ks < 4; ks++)
                    acc[mt][nt] = mfma16(afr2[mt][ks], bfr2[nt][ks], acc[mt][nt]);

#pragma unroll
        for (int nt = 0; nt < 2; nt++) {
            const int j = nt * 16 + lr;
            const int nid = s.nidS[j];
            if (nid >= 0) {
                const float bs = s.biasS[j];
#pragma unroll
                for (int mt = 0; mt < 2; mt++) {
                    const int tt = wv * 32 + mt * 16 + lh * 4;
#pragma unroll
                    for (int jr = 0; jr < 4; jr++)
                        out[(size_t)(bb2 * 128 + tt + jr) * NN + nid] = acc[mt][nt][jr] + bs;
                }
            }
        }
    }

    // ---- dead neurons -> zeros (slot-0 blocks) ----
    if (slot == 0) {
        const int dc = s.deadcnt;
        for (int idx = tid; idx < dc * 128; idx += 256) {
            const int j = idx >> 7, t = idx & 127;
            const int n = s.list[2047 - j];
            out[(size_t)(bb2 * 128 + t) * NN + n] = 0.f;
        }
    }
}

extern "C" void kernel_launch(void* const* d_in, const int* in_sizes, int n_in,
                              void* d_out, int out_size, void* d_ws, size_t ws_size,
                              hipStream_t stream)
{
    const float* U              = (const float*)d_in[0];
    const int*   neuron_regions = (const int*)d_in[1];
    const int*   eids           = (const int*)d_in[2];
    const int*   r_map          = (const int*)d_in[3];
    const float* neuron_slot    = (const float*)d_in[4];
    const float* region_emb     = (const float*)d_in[5];
    const float* eid_emb        = (const float*)d_in[6];
    const float* ln_gamma       = (const float*)d_in[7];
    const float* ln_beta        = (const float*)d_in[8];
    const float* W1             = (const float*)d_in[9];
    const float* b1             = (const float*)d_in[10];
    const float* W2             = (const float*)d_in[11];
    const float* b2             = (const float*)d_in[12];

    char* ws = (char*)d_ws;
    unsigned short* w_ws    = (unsigned short*)(ws);               // 2 MiB
    float*          bias_ws = (float*)(ws + 0x200000);             // 32 KiB
    unsigned short* W1T     = (unsigned short*)(ws + 0x208000);    // 64 KiB
    unsigned short* W2T     = (unsigned short*)(ws + 0x218000);    // 64 KiB
    float*          w2col   = (float*)(ws + 0x228000);             // 1 KiB
    int*            bar     = (int*)(ws + 0x600000);               // barrier counters
    float* outp = (float*)d_out;

    hipMemsetAsync(bar, 0, 16, stream);
    hipLaunchKernelGGL(fused_kernel, dim3(256), dim3(256), 0, stream,
                       U, neuron_regions, eids, r_map, neuron_slot, region_emb,
                       eid_emb, ln_gamma, ln_beta, W1, b1, W2, b2,
                       W1T, W2T, w2col, w_ws, bias_ws, bar, outp);
}

// Round 7
// 72.048 us; speedup vs baseline: 1.2569x; 1.2569x over previous
//
#include <hip/hip_runtime.h>
#include <hip/hip_bf16.h>
#include <math.h>

#define DEV __device__ __forceinline__

typedef __attribute__((ext_vector_type(8))) short short8v;
typedef __attribute__((ext_vector_type(4))) float f32x4;

DEV unsigned short f2bf(float x) {
    unsigned u = __float_as_uint(x);
    return (unsigned short)((u + 0x7fffu + ((u >> 16) & 1u)) >> 16);
}
DEV unsigned pack2(float lo, float hi) {
    return ((unsigned)f2bf(hi) << 16) | (unsigned)f2bf(lo);
}
DEV f32x4 mfma16(short8v a, short8v b, f32x4 c) {
    return __builtin_amdgcn_mfma_f32_16x16x32_bf16(a, b, c, 0, 0, 0);
}

#define NN 2048

// ==================================================================
// prep (65 blocks): W1[128][256] -> W1T bf16 [256][128];
//                   W2[256][129] cols 0..127 -> W2T bf16 [128][256];
//                   w2col[256] = W2[:,128].
// ==================================================================
__global__ __launch_bounds__(256, 1) void prep_kernel(
    const float* __restrict__ W1, const float* __restrict__ W2,
    unsigned short* __restrict__ W1T, unsigned short* __restrict__ W2T,
    float* __restrict__ w2col)
{
    __shared__ __align__(16) float T[32][33];
    const int tid = threadIdx.x;
    const int bid = blockIdx.x;

    if (bid < 32) {
        const int tr = bid >> 3, tc = bid & 7;
#pragma unroll
        for (int p = 0; p < 4; p++) {
            const int i = p * 8 + (tid >> 5), j = tid & 31;
            T[i][j] = W1[(tr * 32 + i) * 256 + tc * 32 + j];
        }
        __syncthreads();
#pragma unroll
        for (int p = 0; p < 4; p++) {
            const int i = p * 8 + (tid >> 5), j = tid & 31;
            W1T[(tc * 32 + i) * 128 + tr * 32 + j] = f2bf(T[j][i]);
        }
    } else if (bid < 64) {
        const int bb = bid - 32, tr = bb >> 2, tc = bb & 3;
#pragma unroll
        for (int p = 0; p < 4; p++) {
            const int i = p * 8 + (tid >> 5), j = tid & 31;
            T[i][j] = W2[(tr * 32 + i) * 129 + tc * 32 + j];
        }
        __syncthreads();
#pragma unroll
        for (int p = 0; p < 4; p++) {
            const int i = p * 8 + (tid >> 5), j = tid & 31;
            W2T[(tc * 32 + i) * 256 + tr * 32 + j] = f2bf(T[j][i]);
        }
    } else {
        w2col[tid] = W2[tid * 129 + 128];
    }
}

// ==================================================================
// main: 512 blocks = (b, slot, t-half). Per block: stage U slice,
// compact own neurons, then per 32-neuron chunk: LN -> GEMM1+GELU ->
// GEMM2 -> bounce -> decode MFMA -> scatter store. No inter-block deps.
// ==================================================================
struct __align__(16) Smem {
    unsigned short Ubf[64][136];   // 17408 B staged U (bf16)
    unsigned short hT[32][136];    //  8704 B LN out; reused as decode-B (Wl)
    unsigned short H1[32][264];    // 16896 B gelu(hW1+b1)
    int list[2048];                //  8192 B own neurons (dead from top)
    int rmapS[128];
    float biasS[32];
    int cnt, deadcnt;
};                                  // ~51.6 KB -> 2 blocks/CU (grid-limited)

__global__ __launch_bounds__(256, 1) void main_kernel(
    const float* __restrict__ U, const int* __restrict__ neuron_regions,
    const int* __restrict__ eids, const int* __restrict__ r_map,
    const float* __restrict__ neuron_slot, const float* __restrict__ region_emb,
    const float* __restrict__ eid_emb, const float* __restrict__ ln_gamma,
    const float* __restrict__ ln_beta, const float* __restrict__ b1,
    const float* __restrict__ b2, const unsigned short* __restrict__ W1T,
    const unsigned short* __restrict__ W2T, const float* __restrict__ w2col,
    float* __restrict__ out)
{
    __shared__ Smem s;
    const int tid = threadIdx.x;
    const int bid = blockIdx.x;
    const int bb = bid >> 7, slot = (bid >> 1) & 63, thalf = bid & 1;
    const int t0 = thalf * 64;

    if (tid == 0) { s.cnt = 0; s.deadcnt = 0; }
    if (tid < 128) s.rmapS[tid] = r_map[tid];

    // ---- stage U[bb, t0..t0+63, slot, :] -> Ubf (issued first, used last) ----
    {
        const int t = tid >> 2, q = tid & 3;
        const float* src = U + ((size_t)((bb * 128 + t0 + t) * 64 + slot)) * 128 + q * 32;
        unsigned short* dst = &s.Ubf[t][q * 32];
#pragma unroll
        for (int j = 0; j < 8; j++) {
            float4 v = ((const float4*)src)[j];
            ((uint2*)dst)[j] = make_uint2(pack2(v.x, v.y), pack2(v.z, v.w));
        }
    }
    __syncthreads();

    // ---- compact this (bb,slot)'s neurons; dead (slot 0 only) from top ----
    for (int n = tid; n < NN; n += 256) {
        int reg = min(max(neuron_regions[bb * NN + n], 0), 127);
        int lrv = s.rmapS[reg];
        if (lrv >= 0) {
            if (min(lrv, 63) == slot) { int p = atomicAdd(&s.cnt, 1); s.list[p] = n; }
        } else if (slot == 0) {
            int p = atomicAdd(&s.deadcnt, 1); s.list[2047 - p] = n;
        }
    }
    __syncthreads();

    const int cnt = s.cnt;
    const int wv = tid >> 6, l = tid & 63;
    const int lr = l & 15, lh = l >> 4;

    // decode A-fragments (U rows), held in regs for the whole kernel
    short8v afr2[4];
#pragma unroll
    for (int ks = 0; ks < 4; ks++)
        afr2[ks] = *(const short8v*)&s.Ubf[wv * 16 + lr][ks * 32 + lh * 8];

    const int eid = min(max(eids[bb], 0), 255);
    const float b2last = b2[128];

    const int nChunks = (cnt + 31) >> 5;
#pragma unroll 1
    for (int c = 0; c < nChunks; c++) {
        const int base = c * 32;
        const int cc = min(cnt - base, 32);

        // ---- LN for 32 gathered rows -> hT; zero biasS ----
        if (tid < 32) s.biasS[tid] = 0.f;
        {
            const int rr = tid >> 3, q = tid & 7;   // 32 rows x 8 lanes x 16 elems
            const int n = s.list[base + (rr < cc ? rr : 0)];
            const int nr = min(max(neuron_regions[bb * NN + n], 0), 127);
            const float* ns = neuron_slot + n * 128 + q * 16;
            const float* re = region_emb + nr * 128 + q * 16;
            const float* ee = eid_emb + eid * 128 + q * 16;
            float e[16];
#pragma unroll
            for (int i = 0; i < 4; i++) {
                float4 a = ((const float4*)ns)[i];
                float4 cte = ((const float4*)re)[i];
                float4 d = ((const float4*)ee)[i];
                e[i * 4 + 0] = a.x + cte.x + d.x;
                e[i * 4 + 1] = a.y + cte.y + d.y;
                e[i * 4 + 2] = a.z + cte.z + d.z;
                e[i * 4 + 3] = a.w + cte.w + d.w;
            }
            float sm = 0.f, s2 = 0.f;
#pragma unroll
            for (int i = 0; i < 16; i++) { sm += e[i]; s2 += e[i] * e[i]; }
            sm += __shfl_xor(sm, 1); s2 += __shfl_xor(s2, 1);
            sm += __shfl_xor(sm, 2); s2 += __shfl_xor(s2, 2);
            sm += __shfl_xor(sm, 4); s2 += __shfl_xor(s2, 4);
            const float mu = sm * (1.f / 128.f);
            const float var = s2 * (1.f / 128.f) - mu * mu;
            const float rstd = rsqrtf(var + 1e-5f);
            float hv[16];
#pragma unroll
            for (int i = 0; i < 4; i++) {
                float4 g = ((const float4*)(ln_gamma + q * 16))[i];
                float4 btv = ((const float4*)(ln_beta + q * 16))[i];
                hv[i * 4 + 0] = (e[i * 4 + 0] - mu) * rstd * g.x + btv.x;
                hv[i * 4 + 1] = (e[i * 4 + 1] - mu) * rstd * g.y + btv.y;
                hv[i * 4 + 2] = (e[i * 4 + 2] - mu) * rstd * g.z + btv.z;
                hv[i * 4 + 3] = (e[i * 4 + 3] - mu) * rstd * g.w + btv.w;
            }
            uint4 pkA, pkB;
            pkA.x = pack2(hv[0], hv[1]);  pkA.y = pack2(hv[2], hv[3]);
            pkA.z = pack2(hv[4], hv[5]);  pkA.w = pack2(hv[6], hv[7]);
            pkB.x = pack2(hv[8], hv[9]);  pkB.y = pack2(hv[10], hv[11]);
            pkB.z = pack2(hv[12], hv[13]); pkB.w = pack2(hv[14], hv[15]);
            *(uint4*)&s.hT[rr][q * 16] = pkA;
            *(uint4*)&s.hT[rr][q * 16 + 8] = pkB;
        }
        __syncthreads();

        // ---- GEMM1 [32x256] = hT @ W1T + GELU -> H1; bias partials ----
        short8v afr[2][4];
#pragma unroll
        for (int mt = 0; mt < 2; mt++)
#pragma unroll
            for (int ks = 0; ks < 4; ks++)
                afr[mt][ks] = *(const short8v*)&s.hT[mt * 16 + lr][ks * 32 + lh * 8];

        float pb[2][4] = {{0.f, 0.f, 0.f, 0.f}, {0.f, 0.f, 0.f, 0.f}};
#pragma unroll
        for (int nt = 0; nt < 4; nt++) {
            const int n = wv * 64 + nt * 16 + lr;
            short8v bfr[4];
#pragma unroll
            for (int ks = 0; ks < 4; ks++)
                bfr[ks] = *(const short8v*)(W1T + n * 128 + ks * 32 + lh * 8);
            const float b1v = b1[n];
            const float w2cv = w2col[n];
#pragma unroll
            for (int mt = 0; mt < 2; mt++) {
                f32x4 a; a.x = b1v; a.y = b1v; a.z = b1v; a.w = b1v;
#pragma unroll
                for (int ks = 0; ks < 4; ks++) a = mfma16(afr[mt][ks], bfr[ks], a);
#pragma unroll
                for (int j = 0; j < 4; j++) {
                    const float x = a[j];
                    const float g = 0.5f * x * (1.f + erff(x * 0.70710678118654752f));
                    s.H1[mt * 16 + lh * 4 + j][n] = f2bf(g);
                    pb[mt][j] += g * w2cv;
                }
            }
        }
#pragma unroll
        for (int mt = 0; mt < 2; mt++)
#pragma unroll
            for (int j = 0; j < 4; j++) {
                float v = pb[mt][j];
                v += __shfl_xor(v, 1);
                v += __shfl_xor(v, 2);
                v += __shfl_xor(v, 4);
                v += __shfl_xor(v, 8);
                if (lr == 0) atomicAdd(&s.biasS[mt * 16 + lh * 4 + j], v);
            }
        __syncthreads();

        // ---- GEMM2 [32x128] = H1 @ W2T ----
        short8v a2[2][8];
#pragma unroll
        for (int mt = 0; mt < 2; mt++)
#pragma unroll
            for (int ks = 0; ks < 8; ks++)
                a2[mt][ks] = *(const short8v*)&s.H1[mt * 16 + lr][ks * 32 + lh * 8];

        f32x4 acc2[2][2];
#pragma unroll
        for (int nt = 0; nt < 2; nt++) {
            const int n = wv * 32 + nt * 16 + lr;
            short8v bf[8];
#pragma unroll
            for (int ks = 0; ks < 8; ks++)
                bf[ks] = *(const short8v*)(W2T + n * 256 + ks * 32 + lh * 8);
            const float b2v = b2[n];
#pragma unroll
            for (int mt = 0; mt < 2; mt++) {
                f32x4 a; a.x = b2v; a.y = b2v; a.z = b2v; a.w = b2v;
#pragma unroll
                for (int ks = 0; ks < 8; ks++) a = mfma16(a2[mt][ks], bf[ks], a);
                acc2[mt][nt] = a;
            }
        }
        // bounce C2 into hT (as Wl[j][d], bf16) for k-contiguous decode reads
#pragma unroll
        for (int mt = 0; mt < 2; mt++)
#pragma unroll
            for (int nt = 0; nt < 2; nt++)
#pragma unroll
                for (int j = 0; j < 4; j++)
                    s.hT[mt * 16 + lh * 4 + j][wv * 32 + nt * 16 + lr] =
                        f2bf(acc2[mt][nt][j]);
        __syncthreads();

        // ---- decode: C[64t x 32j] = Ubf @ Wl^T; scatter store + bias ----
        short8v bfr2[2][4];
#pragma unroll
        for (int nt = 0; nt < 2; nt++)
#pragma unroll
            for (int ks = 0; ks < 4; ks++)
                bfr2[nt][ks] = *(const short8v*)&s.hT[nt * 16 + lr][ks * 32 + lh * 8];

        f32x4 dacc[2];
#pragma unroll
        for (int nt = 0; nt < 2; nt++) {
            f32x4 a; a.x = 0.f; a.y = 0.f; a.z = 0.f; a.w = 0.f;
#pragma unroll
            for (int ks = 0; ks < 4; ks++) a = mfma16(afr2[ks], bfr2[nt][ks], a);
            dacc[nt] = a;
        }
#pragma unroll
        for (int nt = 0; nt < 2; nt++) {
            const int j = nt * 16 + lr;
            if (j < cc) {
                const int nid = s.list[base + j];
                const float bs = s.biasS[j] + b2last;
#pragma unroll
                for (int jr = 0; jr < 4; jr++)
                    out[(size_t)(bb * 128 + t0 + wv * 16 + lh * 4 + jr) * NN + nid] =
                        dacc[nt][jr] + bs;
            }
        }
        __syncthreads();   // protect hT/H1/biasS reuse next chunk
    }

    // ---- dead neurons -> zeros (slot-0 blocks, own t-half) ----
    if (slot == 0) {
        const int dc = s.deadcnt;
        for (int idx = tid; idx < dc * 64; idx += 256) {
            const int j = idx >> 6, t = idx & 63;
            out[(size_t)(bb * 128 + t0 + t) * NN + s.list[2047 - j]] = 0.f;
        }
    }
}

extern "C" void kernel_launch(void* const* d_in, const int* in_sizes, int n_in,
                              void* d_out, int out_size, void* d_ws, size_t ws_size,
                              hipStream_t stream)
{
    const float* U              = (const float*)d_in[0];
    const int*   neuron_regions = (const int*)d_in[1];
    const int*   eids           = (const int*)d_in[2];
    const int*   r_map          = (const int*)d_in[3];
    const float* neuron_slot    = (const float*)d_in[4];
    const float* region_emb     = (const float*)d_in[5];
    const float* eid_emb        = (const float*)d_in[6];
    const float* ln_gamma       = (const float*)d_in[7];
    const float* ln_beta        = (const float*)d_in[8];
    const float* W1             = (const float*)d_in[9];
    const float* b1             = (const float*)d_in[10];
    const float* W2             = (const float*)d_in[11];
    const float* b2             = (const float*)d_in[12];

    char* ws = (char*)d_ws;
    unsigned short* W1T   = (unsigned short*)(ws);             // 64 KiB
    unsigned short* W2T   = (unsigned short*)(ws + 0x10000);   // 64 KiB
    float*          w2col = (float*)(ws + 0x30000);            // 1 KiB
    float* outp = (float*)d_out;

    hipLaunchKernelGGL(prep_kernel, dim3(65), dim3(256), 0, stream,
                       W1, W2, W1T, W2T, w2col);
    hipLaunchKernelGGL(main_kernel, dim3(512), dim3(256), 0, stream,
                       U, neuron_regions, eids, r_map, neuron_slot, region_emb,
                       eid_emb, ln_gamma, ln_beta, b1, b2, W1T, W2T, w2col, outp);
}

// Round 8
// 71.294 us; speedup vs baseline: 1.2702x; 1.0106x over previous
//
#include <hip/hip_runtime.h>
#include <hip/hip_bf16.h>
#include <math.h>

#define DEV __device__ __forceinline__

typedef __attribute__((ext_vector_type(8))) short short8v;
typedef __attribute__((ext_vector_type(4))) float f32x4;

DEV unsigned short f2bf(float x) {
    unsigned u = __float_as_uint(x);
    return (unsigned short)((u + 0x7fffu + ((u >> 16) & 1u)) >> 16);
}
DEV unsigned pack2(float lo, float hi) {
    return ((unsigned)f2bf(hi) << 16) | (unsigned)f2bf(lo);
}
DEV f32x4 mfma16(short8v a, short8v b, f32x4 c) {
    return __builtin_amdgcn_mfma_f32_16x16x32_bf16(a, b, c, 0, 0, 0);
}

#define NN 2048

// ==================================================================
// prep: blocks 0..31  W1 -> W1T bf16 [256][128]
//       blocks 32..63 W2 cols0..127 -> W2T bf16 [128][256]
//       block  64     w2col = W2[:,128]
//       blocks 65..68 per-b counting sort of neurons by slot (order/offs)
// ==================================================================
__global__ __launch_bounds__(256, 1) void prep_kernel(
    const float* __restrict__ W1, const float* __restrict__ W2,
    const int* __restrict__ r_map, const int* __restrict__ neuron_regions,
    unsigned short* __restrict__ W1T, unsigned short* __restrict__ W2T,
    float* __restrict__ w2col, int* __restrict__ order, int* __restrict__ offs)
{
    __shared__ __align__(16) float T[32][33];
    __shared__ int hist[65], starts[66], cursor[65];
    const int tid = threadIdx.x;
    const int bid = blockIdx.x;

    if (bid < 32) {
        const int tr = bid >> 3, tc = bid & 7;
#pragma unroll
        for (int p = 0; p < 4; p++) {
            const int i = p * 8 + (tid >> 5), j = tid & 31;
            T[i][j] = W1[(tr * 32 + i) * 256 + tc * 32 + j];
        }
        __syncthreads();
#pragma unroll
        for (int p = 0; p < 4; p++) {
            const int i = p * 8 + (tid >> 5), j = tid & 31;
            W1T[(tc * 32 + i) * 128 + tr * 32 + j] = f2bf(T[j][i]);
        }
    } else if (bid < 64) {
        const int bb = bid - 32, tr = bb >> 2, tc = bb & 3;
#pragma unroll
        for (int p = 0; p < 4; p++) {
            const int i = p * 8 + (tid >> 5), j = tid & 31;
            T[i][j] = W2[(tr * 32 + i) * 129 + tc * 32 + j];
        }
        __syncthreads();
#pragma unroll
        for (int p = 0; p < 4; p++) {
            const int i = p * 8 + (tid >> 5), j = tid & 31;
            W2T[(tc * 32 + i) * 256 + tr * 32 + j] = f2bf(T[j][i]);
        }
    } else if (bid == 64) {
        w2col[tid] = W2[tid * 129 + 128];
    } else {
        const int b = bid - 65;
        for (int i = tid; i < 65; i += 256) hist[i] = 0;
        __syncthreads();
        for (int n = tid; n < NN; n += 256) {
            int nr = min(max(neuron_regions[b * NN + n], 0), 127);
            int lr = r_map[nr];
            int bin = (lr < 0) ? 64 : min(lr, 63);
            atomicAdd(&hist[bin], 1);
        }
        __syncthreads();
        if (tid == 0) {
            int run = 0;
            for (int i = 0; i < 65; i++) { starts[i] = run; cursor[i] = run; run += hist[i]; }
            starts[65] = run;
        }
        __syncthreads();
        for (int i = tid; i < 66; i += 256) offs[b * 66 + i] = starts[i];
        for (int n = tid; n < NN; n += 256) {
            int nr = min(max(neuron_regions[b * NN + n], 0), 127);
            int lr = r_map[nr];
            int bin = (lr < 0) ? 64 : min(lr, 63);
            int pos = atomicAdd(&cursor[bin], 1);
            order[b * NN + pos] = n;
        }
    }
}

// ==================================================================
// main: 512 blocks = (b, slot, t-half). Fully local: stage U slice,
// then per 32-neuron chunk (list from precomputed order): LN ->
// GEMM1+GELU -> GEMM2 -> bounce -> decode MFMA -> scatter store.
// No per-block compaction atomics, no inter-block deps.
// ==================================================================
struct __align__(16) Smem {
    unsigned short Ubf[64][136];   // 17408 B staged U (bf16)
    unsigned short hT[32][136];    //  8704 B LN out; reused as decode-B (Wl)
    unsigned short H1[32][264];    // 16896 B gelu(hW1+b1)
    float biasS[32];
};                                  // ~43.1 KB -> 3 blocks/CU by LDS

__global__ __launch_bounds__(256, 1) void main_kernel(
    const float* __restrict__ U, const int* __restrict__ order,
    const int* __restrict__ offs, const int* __restrict__ neuron_regions,
    const int* __restrict__ eids, const float* __restrict__ neuron_slot,
    const float* __restrict__ region_emb, const float* __restrict__ eid_emb,
    const float* __restrict__ ln_gamma, const float* __restrict__ ln_beta,
    const float* __restrict__ b1, const float* __restrict__ b2,
    const unsigned short* __restrict__ W1T, const unsigned short* __restrict__ W2T,
    const float* __restrict__ w2col, float* __restrict__ out)
{
    __shared__ Smem s;
    const int tid = threadIdx.x;
    const int bid = blockIdx.x;
    const int bb = bid >> 7, slot = (bid >> 1) & 63, thalf = bid & 1;
    const int t0 = thalf * 64;

    // ---- stage U[bb, t0..t0+63, slot, :] -> Ubf (issued first, used last) ----
    {
        const int t = tid >> 2, q = tid & 3;
        const float* src = U + ((size_t)((bb * 128 + t0 + t) * 64 + slot)) * 128 + q * 32;
        unsigned short* dst = &s.Ubf[t][q * 32];
#pragma unroll
        for (int j = 0; j < 8; j++) {
            float4 v = ((const float4*)src)[j];
            ((uint2*)dst)[j] = make_uint2(pack2(v.x, v.y), pack2(v.z, v.w));
        }
    }

    const int s0 = offs[bb * 66 + slot];
    const int cnt = offs[bb * 66 + slot + 1] - s0;
    const int eid = min(max(eids[bb], 0), 255);
    const float b2last = b2[128];
    __syncthreads();

    const int wv = tid >> 6, l = tid & 63;
    const int lr = l & 15, lh = l >> 4;

    // decode A-fragments (U rows), held in regs for the whole kernel
    short8v afr2[4];
#pragma unroll
    for (int ks = 0; ks < 4; ks++)
        afr2[ks] = *(const short8v*)&s.Ubf[wv * 16 + lr][ks * 32 + lh * 8];

    const int nChunks = (cnt + 31) >> 5;
#pragma unroll 1
    for (int c = 0; c < nChunks; c++) {
        const int base = c * 32;
        const int cc = min(cnt - base, 32);

        // ---- LN for 32 gathered rows -> hT; zero biasS ----
        if (tid < 32) s.biasS[tid] = 0.f;
        {
            const int rr = tid >> 3, q = tid & 7;   // 32 rows x 8 lanes x 16 elems
            const int n = order[bb * NN + s0 + base + (rr < cc ? rr : 0)];
            const int nr = min(max(neuron_regions[bb * NN + n], 0), 127);
            const float* ns = neuron_slot + n * 128 + q * 16;
            const float* re = region_emb + nr * 128 + q * 16;
            const float* ee = eid_emb + eid * 128 + q * 16;
            float e[16];
#pragma unroll
            for (int i = 0; i < 4; i++) {
                float4 a = ((const float4*)ns)[i];
                float4 cte = ((const float4*)re)[i];
                float4 d = ((const float4*)ee)[i];
                e[i * 4 + 0] = a.x + cte.x + d.x;
                e[i * 4 + 1] = a.y + cte.y + d.y;
                e[i * 4 + 2] = a.z + cte.z + d.z;
                e[i * 4 + 3] = a.w + cte.w + d.w;
            }
            float sm = 0.f, s2 = 0.f;
#pragma unroll
            for (int i = 0; i < 16; i++) { sm += e[i]; s2 += e[i] * e[i]; }
            sm += __shfl_xor(sm, 1); s2 += __shfl_xor(s2, 1);
            sm += __shfl_xor(sm, 2); s2 += __shfl_xor(s2, 2);
            sm += __shfl_xor(sm, 4); s2 += __shfl_xor(s2, 4);
            const float mu = sm * (1.f / 128.f);
            const float var = s2 * (1.f / 128.f) - mu * mu;
            const float rstd = rsqrtf(var + 1e-5f);
            float hv[16];
#pragma unroll
            for (int i = 0; i < 4; i++) {
                float4 g = ((const float4*)(ln_gamma + q * 16))[i];
                float4 btv = ((const float4*)(ln_beta + q * 16))[i];
                hv[i * 4 + 0] = (e[i * 4 + 0] - mu) * rstd * g.x + btv.x;
                hv[i * 4 + 1] = (e[i * 4 + 1] - mu) * rstd * g.y + btv.y;
                hv[i * 4 + 2] = (e[i * 4 + 2] - mu) * rstd * g.z + btv.z;
                hv[i * 4 + 3] = (e[i * 4 + 3] - mu) * rstd * g.w + btv.w;
            }
            uint4 pkA, pkB;
            pkA.x = pack2(hv[0], hv[1]);  pkA.y = pack2(hv[2], hv[3]);
            pkA.z = pack2(hv[4], hv[5]);  pkA.w = pack2(hv[6], hv[7]);
            pkB.x = pack2(hv[8], hv[9]);  pkB.y = pack2(hv[10], hv[11]);
            pkB.z = pack2(hv[12], hv[13]); pkB.w = pack2(hv[14], hv[15]);
            *(uint4*)&s.hT[rr][q * 16] = pkA;
            *(uint4*)&s.hT[rr][q * 16 + 8] = pkB;
        }
        __syncthreads();

        // ---- GEMM1 [32x256] = hT @ W1T + GELU -> H1; bias partials ----
        short8v afr[2][4];
#pragma unroll
        for (int mt = 0; mt < 2; mt++)
#pragma unroll
            for (int ks = 0; ks < 4; ks++)
                afr[mt][ks] = *(const short8v*)&s.hT[mt * 16 + lr][ks * 32 + lh * 8];

        float pb[2][4] = {{0.f, 0.f, 0.f, 0.f}, {0.f, 0.f, 0.f, 0.f}};
#pragma unroll
        for (int nt = 0; nt < 4; nt++) {
            const int n = wv * 64 + nt * 16 + lr;
            short8v bfr[4];
#pragma unroll
            for (int ks = 0; ks < 4; ks++)
                bfr[ks] = *(const short8v*)(W1T + n * 128 + ks * 32 + lh * 8);
            const float b1v = b1[n];
            const float w2cv = w2col[n];
#pragma unroll
            for (int mt = 0; mt < 2; mt++) {
                f32x4 a; a.x = b1v; a.y = b1v; a.z = b1v; a.w = b1v;
#pragma unroll
                for (int ks = 0; ks < 4; ks++) a = mfma16(afr[mt][ks], bfr[ks], a);
#pragma unroll
                for (int j = 0; j < 4; j++) {
                    const float x = a[j];
                    const float g = 0.5f * x * (1.f + erff(x * 0.70710678118654752f));
                    s.H1[mt * 16 + lh * 4 + j][n] = f2bf(g);
                    pb[mt][j] += g * w2cv;
                }
            }
        }
#pragma unroll
        for (int mt = 0; mt < 2; mt++)
#pragma unroll
            for (int j = 0; j < 4; j++) {
                float v = pb[mt][j];
                v += __shfl_xor(v, 1);
                v += __shfl_xor(v, 2);
                v += __shfl_xor(v, 4);
                v += __shfl_xor(v, 8);
                if (lr == 0) atomicAdd(&s.biasS[mt * 16 + lh * 4 + j], v);
            }
        __syncthreads();

        // ---- GEMM2 [32x128] = H1 @ W2T ----
        short8v a2[2][8];
#pragma unroll
        for (int mt = 0; mt < 2; mt++)
#pragma unroll
            for (int ks = 0; ks < 8; ks++)
                a2[mt][ks] = *(const short8v*)&s.H1[mt * 16 + lr][ks * 32 + lh * 8];

        f32x4 acc2[2][2];
#pragma unroll
        for (int nt = 0; nt < 2; nt++) {
            const int n = wv * 32 + nt * 16 + lr;
            short8v bf[8];
#pragma unroll
            for (int ks = 0; ks < 8; ks++)
                bf[ks] = *(const short8v*)(W2T + n * 256 + ks * 32 + lh * 8);
            const float b2v = b2[n];
#pragma unroll
            for (int mt = 0; mt < 2; mt++) {
                f32x4 a; a.x = b2v; a.y = b2v; a.z = b2v; a.w = b2v;
#pragma unroll
                for (int ks = 0; ks < 8; ks++) a = mfma16(a2[mt][ks], bf[ks], a);
                acc2[mt][nt] = a;
            }
        }
        // bounce C2 into hT (as Wl[j][d], bf16) for k-contiguous decode reads
        // (safe: hT last read before the post-GEMM1 barrier)
#pragma unroll
        for (int mt = 0; mt < 2; mt++)
#pragma unroll
            for (int nt = 0; nt < 2; nt++)
#pragma unroll
                for (int j = 0; j < 4; j++)
                    s.hT[mt * 16 + lh * 4 + j][wv * 32 + nt * 16 + lr] =
                        f2bf(acc2[mt][nt][j]);
        __syncthreads();

        // ---- decode: C[64t x 32j] = Ubf @ Wl^T; scatter store + bias ----
        short8v bfr2[2][4];
#pragma unroll
        for (int nt = 0; nt < 2; nt++)
#pragma unroll
            for (int ks = 0; ks < 4; ks++)
                bfr2[nt][ks] = *(const short8v*)&s.hT[nt * 16 + lr][ks * 32 + lh * 8];

        f32x4 dacc[2];
#pragma unroll
        for (int nt = 0; nt < 2; nt++) {
            f32x4 a; a.x = 0.f; a.y = 0.f; a.z = 0.f; a.w = 0.f;
#pragma unroll
            for (int ks = 0; ks < 4; ks++) a = mfma16(afr2[ks], bfr2[nt][ks], a);
            dacc[nt] = a;
        }
#pragma unroll
        for (int nt = 0; nt < 2; nt++) {
            const int j = nt * 16 + lr;
            if (j < cc) {
                const int nid = order[bb * NN + s0 + base + j];
                const float bs = s.biasS[j] + b2last;
#pragma unroll
                for (int jr = 0; jr < 4; jr++)
                    out[(size_t)(bb * 128 + t0 + wv * 16 + lh * 4 + jr) * NN + nid] =
                        dacc[nt][jr] + bs;
            }
        }
        __syncthreads();   // protect hT/H1/biasS reuse next chunk
    }

    // ---- dead neurons -> zeros (slot-0 blocks, own t-half) ----
    if (slot == 0) {
        const int d0 = offs[bb * 66 + 64];
        const int dc = offs[bb * 66 + 65] - d0;
        for (int idx = tid; idx < dc * 64; idx += 256) {
            const int j = idx >> 6, t = idx & 63;
            out[(size_t)(bb * 128 + t0 + t) * NN + order[bb * NN + d0 + j]] = 0.f;
        }
    }
}

extern "C" void kernel_launch(void* const* d_in, const int* in_sizes, int n_in,
                              void* d_out, int out_size, void* d_ws, size_t ws_size,
                              hipStream_t stream)
{
    const float* U              = (const float*)d_in[0];
    const int*   neuron_regions = (const int*)d_in[1];
    const int*   eids           = (const int*)d_in[2];
    const int*   r_map          = (const int*)d_in[3];
    const float* neuron_slot    = (const float*)d_in[4];
    const float* region_emb     = (const float*)d_in[5];
    const float* eid_emb        = (const float*)d_in[6];
    const float* ln_gamma       = (const float*)d_in[7];
    const float* ln_beta        = (const float*)d_in[8];
    const float* W1             = (const float*)d_in[9];
    const float* b1             = (const float*)d_in[10];
    const float* W2             = (const float*)d_in[11];
    const float* b2             = (const float*)d_in[12];

    char* ws = (char*)d_ws;
    unsigned short* W1T   = (unsigned short*)(ws);             // 64 KiB
    unsigned short* W2T   = (unsigned short*)(ws + 0x10000);   // 64 KiB
    float*          w2col = (float*)(ws + 0x20000);            // 1 KiB
    int*            order = (int*)(ws + 0x21000);              // 32 KiB
    int*            offs  = (int*)(ws + 0x29000);              // ~1 KiB
    float* outp = (float*)d_out;

    hipLaunchKernelGGL(prep_kernel, dim3(69), dim3(256), 0, stream,
                       W1, W2, r_map, neuron_regions, W1T, W2T, w2col, order, offs);
    hipLaunchKernelGGL(main_kernel, dim3(512), dim3(256), 0, stream,
                       U, order, offs, neuron_regions, eids, neuron_slot,
                       region_emb, eid_emb, ln_gamma, ln_beta, b1, b2,
                       W1T, W2T, w2col, outp);
}

// Round 10
// 58.817 us; speedup vs baseline: 1.5397x; 1.2121x over previous
//
#include <hip/hip_runtime.h>
#include <hip/hip_bf16.h>
#include <math.h>

#define DEV __device__ __forceinline__

typedef __attribute__((ext_vector_type(8))) short short8v;
typedef __attribute__((ext_vector_type(4))) float f32x4;

DEV unsigned short f2bf(float x) {
    unsigned u = __float_as_uint(x);
    return (unsigned short)((u + 0x7fffu + ((u >> 16) & 1u)) >> 16);
}
DEV unsigned pack2(float lo, float hi) {
    return ((unsigned)f2bf(hi) << 16) | (unsigned)f2bf(lo);
}
DEV f32x4 mfma16(short8v a, short8v b, f32x4 c) {
    return __builtin_amdgcn_mfma_f32_16x16x32_bf16(a, b, c, 0, 0, 0);
}

// Exact-GELU via Abramowitz-Stegun 7.1.26 erf (|err| <= 1.5e-7), ~16 VALU ops,
// no branches. Replaces libm erff (~40+ ops, divergent).
DEV float gelu_fast(float x) {
    const float z  = x * 0.70710678118654752f;
    const float az = fabsf(z);
    const float t  = __builtin_amdgcn_rcpf(fmaf(0.3275911f, az, 1.0f));
    float p = fmaf(t, 1.061405429f, -1.453152027f);
    p = fmaf(t, p, 1.421413741f);
    p = fmaf(t, p, -0.284496736f);
    p = fmaf(t, p, 0.254829592f);
    p = p * t;
    const float E = __builtin_amdgcn_exp2f(z * z * -1.4426950408889634f);
    const float erf_az = fmaf(-p, E, 1.0f);
    const float erf_z  = copysignf(erf_az, z);
    const float hx = 0.5f * x;
    return fmaf(hx, erf_z, hx);
}

#define NN 2048

// ==================================================================
// prep: blocks 0..31  W1 -> W1T bf16 [256][128]
//       blocks 32..63 W2 cols0..127 -> W2T bf16 [128][256]
//       block  64     w2col = W2[:,128]
//       blocks 65..68 per-b counting sort of neurons by slot (order/offs)
// ==================================================================
__global__ __launch_bounds__(256, 1) void prep_kernel(
    const float* __restrict__ W1, const float* __restrict__ W2,
    const int* __restrict__ r_map, const int* __restrict__ neuron_regions,
    unsigned short* __restrict__ W1T, unsigned short* __restrict__ W2T,
    float* __restrict__ w2col, int* __restrict__ order, int* __restrict__ offs)
{
    __shared__ __align__(16) float T[32][33];
    __shared__ int hist[65], starts[66], cursor[65];
    const int tid = threadIdx.x;
    const int bid = blockIdx.x;

    if (bid < 32) {
        const int tr = bid >> 3, tc = bid & 7;
#pragma unroll
        for (int p = 0; p < 4; p++) {
            const int i = p * 8 + (tid >> 5), j = tid & 31;
            T[i][j] = W1[(tr * 32 + i) * 256 + tc * 32 + j];
        }
        __syncthreads();
#pragma unroll
        for (int p = 0; p < 4; p++) {
            const int i = p * 8 + (tid >> 5), j = tid & 31;
            W1T[(tc * 32 + i) * 128 + tr * 32 + j] = f2bf(T[j][i]);
        }
    } else if (bid < 64) {
        const int bb = bid - 32, tr = bb >> 2, tc = bb & 3;
#pragma unroll
        for (int p = 0; p < 4; p++) {
            const int i = p * 8 + (tid >> 5), j = tid & 31;
            T[i][j] = W2[(tr * 32 + i) * 129 + tc * 32 + j];
        }
        __syncthreads();
#pragma unroll
        for (int p = 0; p < 4; p++) {
            const int i = p * 8 + (tid >> 5), j = tid & 31;
            W2T[(tc * 32 + i) * 256 + tr * 32 + j] = f2bf(T[j][i]);
        }
    } else if (bid == 64) {
        w2col[tid] = W2[tid * 129 + 128];
    } else {
        const int b = bid - 65;
        for (int i = tid; i < 65; i += 256) hist[i] = 0;
        __syncthreads();
        for (int n = tid; n < NN; n += 256) {
            int nr = min(max(neuron_regions[b * NN + n], 0), 127);
            int lr = r_map[nr];
            int bin = (lr < 0) ? 64 : min(lr, 63);
            atomicAdd(&hist[bin], 1);
        }
        __syncthreads();
        if (tid == 0) {
            int run = 0;
            for (int i = 0; i < 65; i++) { starts[i] = run; cursor[i] = run; run += hist[i]; }
            starts[65] = run;
        }
        __syncthreads();
        for (int i = tid; i < 66; i += 256) offs[b * 66 + i] = starts[i];
        for (int n = tid; n < NN; n += 256) {
            int nr = min(max(neuron_regions[b * NN + n], 0), 127);
            int lr = r_map[nr];
            int bin = (lr < 0) ? 64 : min(lr, 63);
            int pos = atomicAdd(&cursor[bin], 1);
            order[b * NN + pos] = n;
        }
    }
}

// ==================================================================
// main: 512 blocks = (b, slot, t-half). Fully local: stage U slice,
// then per 32-neuron chunk (list from precomputed order): LN ->
// GEMM1+GELU -> GEMM2 -> bounce -> decode MFMA -> scatter store.
// When cc<=16 only the first 16-row half is computed (uniform branch).
// ==================================================================
struct __align__(16) Smem {
    unsigned short Ubf[64][136];   // 17408 B staged U (bf16)
    unsigned short hT[32][136];    //  8704 B LN out; reused as decode-B (Wl)
    unsigned short H1[32][264];    // 16896 B gelu(hW1+b1)
    float biasS[32];
};                                  // ~43.1 KB -> 3 blocks/CU by LDS

__global__ __launch_bounds__(256, 1) void main_kernel(
    const float* __restrict__ U, const int* __restrict__ order,
    const int* __restrict__ offs, const int* __restrict__ neuron_regions,
    const int* __restrict__ eids, const float* __restrict__ neuron_slot,
    const float* __restrict__ region_emb, const float* __restrict__ eid_emb,
    const float* __restrict__ ln_gamma, const float* __restrict__ ln_beta,
    const float* __restrict__ b1, const float* __restrict__ b2,
    const unsigned short* __restrict__ W1T, const unsigned short* __restrict__ W2T,
    const float* __restrict__ w2col, float* __restrict__ out)
{
    __shared__ Smem s;
    const int tid = threadIdx.x;
    const int bid = blockIdx.x;
    const int bb = bid >> 7, slot = (bid >> 1) & 63, thalf = bid & 1;
    const int t0 = thalf * 64;

    // ---- stage U[bb, t0..t0+63, slot, :] -> Ubf (issued first, used last) ----
    {
        const int t = tid >> 2, q = tid & 3;
        const float* src = U + ((size_t)((bb * 128 + t0 + t) * 64 + slot)) * 128 + q * 32;
        unsigned short* dst = &s.Ubf[t][q * 32];
#pragma unroll
        for (int j = 0; j < 8; j++) {
            float4 v = ((const float4*)src)[j];
            ((uint2*)dst)[j] = make_uint2(pack2(v.x, v.y), pack2(v.z, v.w));
        }
    }

    const int s0 = offs[bb * 66 + slot];
    const int cnt = offs[bb * 66 + slot + 1] - s0;
    const int eid = min(max(eids[bb], 0), 255);
    const float b2last = b2[128];
    __syncthreads();

    const int wv = tid >> 6, l = tid & 63;
    const int lr = l & 15, lh = l >> 4;

    // decode A-fragments (U rows), held in regs for the whole kernel
    short8v afr2[4];
#pragma unroll
    for (int ks = 0; ks < 4; ks++)
        afr2[ks] = *(const short8v*)&s.Ubf[wv * 16 + lr][ks * 32 + lh * 8];

    const int nChunks = (cnt + 31) >> 5;
#pragma unroll 1
    for (int c = 0; c < nChunks; c++) {
        const int base = c * 32;
        const int cc = min(cnt - base, 32);
        const bool full = (cc > 16);   // block-uniform: skip padded 16-row half

        // ---- LN for 32 gathered rows -> hT; zero biasS ----
        if (tid < 32) s.biasS[tid] = 0.f;
        {
            const int rr = tid >> 3, q = tid & 7;   // 32 rows x 8 lanes x 16 elems
            const int n = order[bb * NN + s0 + base + (rr < cc ? rr : 0)];
            const int nr = min(max(neuron_regions[bb * NN + n], 0), 127);
            const float* ns = neuron_slot + n * 128 + q * 16;
            const float* re = region_emb + nr * 128 + q * 16;
            const float* ee = eid_emb + eid * 128 + q * 16;
            float e[16];
#pragma unroll
            for (int i = 0; i < 4; i++) {
                float4 a = ((const float4*)ns)[i];
                float4 cte = ((const float4*)re)[i];
                float4 d = ((const float4*)ee)[i];
                e[i * 4 + 0] = a.x + cte.x + d.x;
                e[i * 4 + 1] = a.y + cte.y + d.y;
                e[i * 4 + 2] = a.z + cte.z + d.z;
                e[i * 4 + 3] = a.w + cte.w + d.w;
            }
            float sm = 0.f, s2 = 0.f;
#pragma unroll
            for (int i = 0; i < 16; i++) { sm += e[i]; s2 += e[i] * e[i]; }
            sm += __shfl_xor(sm, 1); s2 += __shfl_xor(s2, 1);
            sm += __shfl_xor(sm, 2); s2 += __shfl_xor(s2, 2);
            sm += __shfl_xor(sm, 4); s2 += __shfl_xor(s2, 4);
            const float mu = sm * (1.f / 128.f);
            const float var = s2 * (1.f / 128.f) - mu * mu;
            const float rstd = rsqrtf(var + 1e-5f);
            float hv[16];
#pragma unroll
            for (int i = 0; i < 4; i++) {
                float4 g = ((const float4*)(ln_gamma + q * 16))[i];
                float4 btv = ((const float4*)(ln_beta + q * 16))[i];
                hv[i * 4 + 0] = (e[i * 4 + 0] - mu) * rstd * g.x + btv.x;
                hv[i * 4 + 1] = (e[i * 4 + 1] - mu) * rstd * g.y + btv.y;
                hv[i * 4 + 2] = (e[i * 4 + 2] - mu) * rstd * g.z + btv.z;
                hv[i * 4 + 3] = (e[i * 4 + 3] - mu) * rstd * g.w + btv.w;
            }
            uint4 pkA, pkB;
            pkA.x = pack2(hv[0], hv[1]);  pkA.y = pack2(hv[2], hv[3]);
            pkA.z = pack2(hv[4], hv[5]);  pkA.w = pack2(hv[6], hv[7]);
            pkB.x = pack2(hv[8], hv[9]);  pkB.y = pack2(hv[10], hv[11]);
            pkB.z = pack2(hv[12], hv[13]); pkB.w = pack2(hv[14], hv[15]);
            *(uint4*)&s.hT[rr][q * 16] = pkA;
            *(uint4*)&s.hT[rr][q * 16 + 8] = pkB;
        }
        __syncthreads();

        // ---- GEMM1 [32x256] = hT @ W1T + GELU -> H1; bias partials ----
        short8v afr[2][4];
#pragma unroll
        for (int mt = 0; mt < 2; mt++)
#pragma unroll
            for (int ks = 0; ks < 4; ks++)
                afr[mt][ks] = *(const short8v*)&s.hT[mt * 16 + lr][ks * 32 + lh * 8];

        float pb[2][4] = {{0.f, 0.f, 0.f, 0.f}, {0.f, 0.f, 0.f, 0.f}};
#pragma unroll
        for (int nt = 0; nt < 4; nt++) {
            const int n = wv * 64 + nt * 16 + lr;
            short8v bfr[4];
#pragma unroll
            for (int ks = 0; ks < 4; ks++)
                bfr[ks] = *(const short8v*)(W1T + n * 128 + ks * 32 + lh * 8);
            const float b1v = b1[n];
            const float w2cv = w2col[n];
#pragma unroll
            for (int mt = 0; mt < 2; mt++) {
                if (mt == 1 && !full) continue;
                f32x4 a; a.x = b1v; a.y = b1v; a.z = b1v; a.w = b1v;
#pragma unroll
                for (int ks = 0; ks < 4; ks++) a = mfma16(afr[mt][ks], bfr[ks], a);
#pragma unroll
                for (int j = 0; j < 4; j++) {
                    const float g = gelu_fast(a[j]);
                    s.H1[mt * 16 + lh * 4 + j][n] = f2bf(g);
                    pb[mt][j] += g * w2cv;
                }
            }
        }
#pragma unroll
        for (int mt = 0; mt < 2; mt++) {
            if (mt == 1 && !full) continue;
#pragma unroll
            for (int j = 0; j < 4; j++) {
                float v = pb[mt][j];
                v += __shfl_xor(v, 1);
                v += __shfl_xor(v, 2);
                v += __shfl_xor(v, 4);
                v += __shfl_xor(v, 8);
                if (lr == 0) atomicAdd(&s.biasS[mt * 16 + lh * 4 + j], v);
            }
        }
        __syncthreads();

        // ---- GEMM2 [32x128] = H1 @ W2T ----
        short8v a2[2][8];
#pragma unroll
        for (int mt = 0; mt < 2; mt++) {
            if (mt == 1 && !full) continue;
#pragma unroll
            for (int ks = 0; ks < 8; ks++)
                a2[mt][ks] = *(const short8v*)&s.H1[mt * 16 + lr][ks * 32 + lh * 8];
        }

        f32x4 acc2[2][2];
#pragma unroll
        for (int nt = 0; nt < 2; nt++) {
            const int n = wv * 32 + nt * 16 + lr;
            short8v bf[8];
#pragma unroll
            for (int ks = 0; ks < 8; ks++)
                bf[ks] = *(const short8v*)(W2T + n * 256 + ks * 32 + lh * 8);
            const float b2v = b2[n];
#pragma unroll
            for (int mt = 0; mt < 2; mt++) {
                if (mt == 1 && !full) continue;
                f32x4 a; a.x = b2v; a.y = b2v; a.z = b2v; a.w = b2v;
#pragma unroll
                for (int ks = 0; ks < 8; ks++) a = mfma16(a2[mt][ks], bf[ks], a);
                acc2[mt][nt] = a;
            }
        }
        // bounce C2 into hT (as Wl[j][d], bf16) for k-contiguous decode reads
        // (safe: hT last read before the post-GEMM1 barrier; skipped rows
        //  leave stale-but-finite data whose outputs are store-guarded)
#pragma unroll
        for (int mt = 0; mt < 2; mt++) {
            if (mt == 1 && !full) continue;
#pragma unroll
            for (int nt = 0; nt < 2; nt++)
#pragma unroll
                for (int j = 0; j < 4; j++)
                    s.hT[mt * 16 + lh * 4 + j][wv * 32 + nt * 16 + lr] =
                        f2bf(acc2[mt][nt][j]);
        }
        __syncthreads();

        // ---- decode: C[64t x 32j] = Ubf @ Wl^T; scatter store + bias ----
        short8v bfr2[2][4];
#pragma unroll
        for (int nt = 0; nt < 2; nt++)
#pragma unroll
            for (int ks = 0; ks < 4; ks++)
                bfr2[nt][ks] = *(const short8v*)&s.hT[nt * 16 + lr][ks * 32 + lh * 8];

        f32x4 dacc[2];
#pragma unroll
        for (int nt = 0; nt < 2; nt++) {
            f32x4 a; a.x = 0.f; a.y = 0.f; a.z = 0.f; a.w = 0.f;
#pragma unroll
            for (int ks = 0; ks < 4; ks++) a = mfma16(afr2[ks], bfr2[nt][ks], a);
            dacc[nt] = a;
        }
#pragma unroll
        for (int nt = 0; nt < 2; nt++) {
            const int j = nt * 16 + lr;
            if (j < cc) {
                const int nid = order[bb * NN + s0 + base + j];
                const float bs = s.biasS[j] + b2last;
#pragma unroll
                for (int jr = 0; jr < 4; jr++)
                    out[(size_t)(bb * 128 + t0 + wv * 16 + lh * 4 + jr) * NN + nid] =
                        dacc[nt][jr] + bs;
            }
        }
        __syncthreads();   // protect hT/H1/biasS reuse next chunk
    }

    // ---- dead neurons -> zeros (slot-0 blocks, own t-half) ----
    if (slot == 0) {
        const int d0 = offs[bb * 66 + 64];
        const int dc = offs[bb * 66 + 65] - d0;
        for (int idx = tid; idx < dc * 64; idx += 256) {
            const int j = idx >> 6, t = idx & 63;
            out[(size_t)(bb * 128 + t0 + t) * NN + order[bb * NN + d0 + j]] = 0.f;
        }
    }
}

extern "C" void kernel_launch(void* const* d_in, const int* in_sizes, int n_in,
                              void* d_out, int out_size, void* d_ws, size_t ws_size,
                              hipStream_t stream)
{
    const float* U              = (const float*)d_in[0];
    const int*   neuron_regions = (const int*)d_in[1];
    const int*   eids           = (const int*)d_in[2];
    const int*   r_map          = (const int*)d_in[3];
    const float* neuron_slot    = (const float*)d_in[4];
    const float* region_emb     = (const float*)d_in[5];
    const float* eid_emb        = (const float*)d_in[6];
    const float* ln_gamma       = (const float*)d_in[7];
    const float* ln_beta        = (const float*)d_in[8];
    const float* W1             = (const float*)d_in[9];
    const float* b1             = (const float*)d_in[10];
    const float* W2             = (const float*)d_in[11];
    const float* b2             = (const float*)d_in[12];

    char* ws = (char*)d_ws;
    unsigned short* W1T   = (unsigned short*)(ws);             // 64 KiB
    unsigned short* W2T   = (unsigned short*)(ws + 0x10000);   // 64 KiB
    float*          w2col = (float*)(ws + 0x20000);            // 1 KiB
    int*            order = (int*)(ws + 0x21000);              // 32 KiB
    int*            offs  = (int*)(ws + 0x29000);              // ~1 KiB
    float* outp = (float*)d_out;

    hipLaunchKernelGGL(prep_kernel, dim3(69), dim3(256), 0, stream,
                       W1, W2, r_map, neuron_regions, W1T, W2T, w2col, order, offs);
    hipLaunchKernelGGL(main_kernel, dim3(512), dim3(256), 0, stream,
                       U, order, offs, neuron_regions, eids, neuron_slot,
                       region_emb, eid_emb, ln_gamma, ln_beta, b1, b2,
                       W1T, W2T, w2col, outp);
}

// Round 12
// 52.427 us; speedup vs baseline: 1.7273x; 1.1219x over previous
//
#include <hip/hip_runtime.h>
#include <hip/hip_bf16.h>
#include <math.h>

#define DEV __device__ __forceinline__

typedef __attribute__((ext_vector_type(8))) short short8v;
typedef __attribute__((ext_vector_type(4))) float f32x4;

DEV unsigned short f2bf(float x) {
    unsigned u = __float_as_uint(x);
    return (unsigned short)((u + 0x7fffu + ((u >> 16) & 1u)) >> 16);
}
DEV unsigned pack2(float lo, float hi) {
    return ((unsigned)f2bf(hi) << 16) | (unsigned)f2bf(lo);
}
DEV f32x4 mfma16(short8v a, short8v b, f32x4 c) {
    return __builtin_amdgcn_mfma_f32_16x16x32_bf16(a, b, c, 0, 0, 0);
}

// Exact-GELU via Abramowitz-Stegun 7.1.26 erf (|err| <= 1.5e-7), ~16 VALU ops.
DEV float gelu_fast(float x) {
    const float z  = x * 0.70710678118654752f;
    const float az = fabsf(z);
    const float t  = __builtin_amdgcn_rcpf(fmaf(0.3275911f, az, 1.0f));
    float p = fmaf(t, 1.061405429f, -1.453152027f);
    p = fmaf(t, p, 1.421413741f);
    p = fmaf(t, p, -0.284496736f);
    p = fmaf(t, p, 0.254829592f);
    p = p * t;
    const float E = __builtin_amdgcn_exp2f(z * z * -1.4426950408889634f);
    const float erf_az = fmaf(-p, E, 1.0f);
    const float erf_z  = copysignf(erf_az, z);
    const float hx = 0.5f * x;
    return fmaf(hx, erf_z, hx);
}

#define NN 2048

// ==================================================================
// prep: blocks 0..31  W1 -> W1T bf16 [256][128]
//       blocks 32..63 W2 cols0..127 -> W2T bf16 [128][256]
//       block  64     w2col = W2[:,128]
//       blocks 65..68 per-b counting sort by slot + chunk descriptors
// ==================================================================
__global__ __launch_bounds__(256, 1) void prep_kernel(
    const float* __restrict__ W1, const float* __restrict__ W2,
    const int* __restrict__ r_map, const int* __restrict__ neuron_regions,
    unsigned short* __restrict__ W1T, unsigned short* __restrict__ W2T,
    float* __restrict__ w2col, int* __restrict__ order, int* __restrict__ offs,
    int* __restrict__ desc, int* __restrict__ dcount)
{
    __shared__ __align__(16) float T[32][33];
    __shared__ int hist[65], starts[66], cursor[65];
    const int tid = threadIdx.x;
    const int bid = blockIdx.x;

    if (bid < 32) {
        const int tr = bid >> 3, tc = bid & 7;
#pragma unroll
        for (int p = 0; p < 4; p++) {
            const int i = p * 8 + (tid >> 5), j = tid & 31;
            T[i][j] = W1[(tr * 32 + i) * 256 + tc * 32 + j];
        }
        __syncthreads();
#pragma unroll
        for (int p = 0; p < 4; p++) {
            const int i = p * 8 + (tid >> 5), j = tid & 31;
            W1T[(tc * 32 + i) * 128 + tr * 32 + j] = f2bf(T[j][i]);
        }
    } else if (bid < 64) {
        const int bb = bid - 32, tr = bb >> 2, tc = bb & 3;
#pragma unroll
        for (int p = 0; p < 4; p++) {
            const int i = p * 8 + (tid >> 5), j = tid & 31;
            T[i][j] = W2[(tr * 32 + i) * 129 + tc * 32 + j];
        }
        __syncthreads();
#pragma unroll
        for (int p = 0; p < 4; p++) {
            const int i = p * 8 + (tid >> 5), j = tid & 31;
            W2T[(tc * 32 + i) * 256 + tr * 32 + j] = f2bf(T[j][i]);
        }
    } else if (bid == 64) {
        w2col[tid] = W2[tid * 129 + 128];
    } else {
        const int b = bid - 65;
        for (int i = tid; i < 65; i += 256) hist[i] = 0;
        __syncthreads();
        for (int n = tid; n < NN; n += 256) {
            int nr = min(max(neuron_regions[b * NN + n], 0), 127);
            int lr = r_map[nr];
            int bin = (lr < 0) ? 64 : min(lr, 63);
            atomicAdd(&hist[bin], 1);
        }
        __syncthreads();
        if (tid == 0) {
            int run = 0;
            for (int i = 0; i < 65; i++) { starts[i] = run; cursor[i] = run; run += hist[i]; }
            starts[65] = run;
            // chunk descriptors: one per <=32-neuron chunk of each slot
            int k = 0;
            for (int s2 = 0; s2 < 64; s2++) {
                const int len = starts[s2 + 1] - starts[s2];
                for (int base = 0; base < len; base += 32)
                    desc[b * 128 + k++] = s2 | (base << 8);
            }
            dcount[b] = k;
        }
        __syncthreads();
        for (int i = tid; i < 66; i += 256) offs[b * 66 + i] = starts[i];
        for (int n = tid; n < NN; n += 256) {
            int nr = min(max(neuron_regions[b * NN + n], 0), 127);
            int lr = r_map[nr];
            int bin = (lr < 0) ? 64 : min(lr, 63);
            int pos = atomicAdd(&cursor[bin], 1);
            order[b * NN + pos] = n;
        }
    }
}

// ==================================================================
// main: 1024 blocks = (b, t-half, chunk-idx). Each block does exactly
// ONE <=32-neuron chunk: stage U slice + LN -> GEMM1+GELU -> GEMM2 ->
// bounce -> decode MFMA -> scatter store. 3 barriers, no loop.
// Oversubscribed grid (2-3 rounds/CU) hides per-chain latency.
// ==================================================================
struct __align__(16) Smem {
    unsigned short Ubf[64][136];   // 17408 B staged U (bf16)
    unsigned short hT[32][136];    //  8704 B LN out; reused as decode-B (Wl)
    unsigned short H1[32][264];    // 16896 B gelu(hW1+b1)
    float biasS[32];
};                                  // ~43.1 KB

__global__ __launch_bounds__(256, 3) void main_kernel(
    const float* __restrict__ U, const int* __restrict__ order,
    const int* __restrict__ offs, const int* __restrict__ desc,
    const int* __restrict__ dcount, const int* __restrict__ neuron_regions,
    const int* __restrict__ eids, const float* __restrict__ neuron_slot,
    const float* __restrict__ region_emb, const float* __restrict__ eid_emb,
    const float* __restrict__ ln_gamma, const float* __restrict__ ln_beta,
    const float* __restrict__ b1, const float* __restrict__ b2,
    const unsigned short* __restrict__ W1T, const unsigned short* __restrict__ W2T,
    const float* __restrict__ w2col, float* __restrict__ out)
{
    __shared__ Smem s;
    const int tid = threadIdx.x;
    const int bid = blockIdx.x;
    const int bb = bid >> 8, thalf = (bid >> 7) & 1, ci = bid & 127;
    const int t0 = thalf * 64;

    const int dcnt = dcount[bb];
    if (ci > dcnt) return;
    if (ci == dcnt) {   // dead neurons -> zeros for this t-half
        const int d0 = offs[bb * 66 + 64];
        const int dc = offs[bb * 66 + 65] - d0;
        for (int idx = tid; idx < dc * 64; idx += 256) {
            const int j = idx >> 6, t = idx & 63;
            out[(size_t)(bb * 128 + t0 + t) * NN + order[bb * NN + d0 + j]] = 0.f;
        }
        return;
    }

    const int d = desc[bb * 128 + ci];
    const int slot = d & 63;
    const int base = d >> 8;
    const int s0 = offs[bb * 66 + slot];
    const int cnt = offs[bb * 66 + slot + 1] - s0;
    const int cc = min(cnt - base, 32);
    const bool full = (cc > 16);   // block-uniform: skip padded 16-row half

    // ---- stage U[bb, t0..t0+63, slot, :] -> Ubf (issued first) ----
    {
        const int t = tid >> 2, q = tid & 3;
        const float* src = U + ((size_t)((bb * 128 + t0 + t) * 64 + slot)) * 128 + q * 32;
        unsigned short* dst = &s.Ubf[t][q * 32];
#pragma unroll
        for (int j = 0; j < 8; j++) {
            float4 v = ((const float4*)src)[j];
            ((uint2*)dst)[j] = make_uint2(pack2(v.x, v.y), pack2(v.z, v.w));
        }
    }

    const int eid = min(max(eids[bb], 0), 255);
    const float b2last = b2[128];
    if (tid < 32) s.biasS[tid] = 0.f;

    // ---- LN for cc gathered rows -> hT ----
    {
        const int rr = tid >> 3, q = tid & 7;   // 32 rows x 8 lanes x 16 elems
        const int n = order[bb * NN + s0 + base + (rr < cc ? rr : 0)];
        const int nr = min(max(neuron_regions[bb * NN + n], 0), 127);
        const float* ns = neuron_slot + n * 128 + q * 16;
        const float* re = region_emb + nr * 128 + q * 16;
        const float* ee = eid_emb + eid * 128 + q * 16;
        float e[16];
#pragma unroll
        for (int i = 0; i < 4; i++) {
            float4 a = ((const float4*)ns)[i];
            float4 cte = ((const float4*)re)[i];
            float4 dd = ((const float4*)ee)[i];
            e[i * 4 + 0] = a.x + cte.x + dd.x;
            e[i * 4 + 1] = a.y + cte.y + dd.y;
            e[i * 4 + 2] = a.z + cte.z + dd.z;
            e[i * 4 + 3] = a.w + cte.w + dd.w;
        }
        float sm = 0.f, s2 = 0.f;
#pragma unroll
        for (int i = 0; i < 16; i++) { sm += e[i]; s2 += e[i] * e[i]; }
        sm += __shfl_xor(sm, 1); s2 += __shfl_xor(s2, 1);
        sm += __shfl_xor(sm, 2); s2 += __shfl_xor(s2, 2);
        sm += __shfl_xor(sm, 4); s2 += __shfl_xor(s2, 4);
        const float mu = sm * (1.f / 128.f);
        const float var = s2 * (1.f / 128.f) - mu * mu;
        const float rstd = rsqrtf(var + 1e-5f);
        float hv[16];
#pragma unroll
        for (int i = 0; i < 4; i++) {
            float4 g = ((const float4*)(ln_gamma + q * 16))[i];
            float4 btv = ((const float4*)(ln_beta + q * 16))[i];
            hv[i * 4 + 0] = (e[i * 4 + 0] - mu) * rstd * g.x + btv.x;
            hv[i * 4 + 1] = (e[i * 4 + 1] - mu) * rstd * g.y + btv.y;
            hv[i * 4 + 2] = (e[i * 4 + 2] - mu) * rstd * g.z + btv.z;
            hv[i * 4 + 3] = (e[i * 4 + 3] - mu) * rstd * g.w + btv.w;
        }
        uint4 pkA, pkB;
        pkA.x = pack2(hv[0], hv[1]);  pkA.y = pack2(hv[2], hv[3]);
        pkA.z = pack2(hv[4], hv[5]);  pkA.w = pack2(hv[6], hv[7]);
        pkB.x = pack2(hv[8], hv[9]);  pkB.y = pack2(hv[10], hv[11]);
        pkB.z = pack2(hv[12], hv[13]); pkB.w = pack2(hv[14], hv[15]);
        *(uint4*)&s.hT[rr][q * 16] = pkA;
        *(uint4*)&s.hT[rr][q * 16 + 8] = pkB;
    }
    __syncthreads();   // Ubf + hT ready

    const int wv = tid >> 6, l = tid & 63;
    const int lr = l & 15, lh = l >> 4;

    // decode A-fragments (U rows) in regs
    short8v afr2[4];
#pragma unroll
    for (int ks = 0; ks < 4; ks++)
        afr2[ks] = *(const short8v*)&s.Ubf[wv * 16 + lr][ks * 32 + lh * 8];

    // ---- GEMM1 [32x256] = hT @ W1T + GELU -> H1; bias partials ----
    short8v afr[2][4];
#pragma unroll
    for (int mt = 0; mt < 2; mt++)
#pragma unroll
        for (int ks = 0; ks < 4; ks++)
            afr[mt][ks] = *(const short8v*)&s.hT[mt * 16 + lr][ks * 32 + lh * 8];

    float pb[2][4] = {{0.f, 0.f, 0.f, 0.f}, {0.f, 0.f, 0.f, 0.f}};
#pragma unroll
    for (int nt = 0; nt < 4; nt++) {
        const int n = wv * 64 + nt * 16 + lr;
        short8v bfr[4];
#pragma unroll
        for (int ks = 0; ks < 4; ks++)
            bfr[ks] = *(const short8v*)(W1T + n * 128 + ks * 32 + lh * 8);
        const float b1v = b1[n];
        const float w2cv = w2col[n];
#pragma unroll
        for (int mt = 0; mt < 2; mt++) {
            if (mt == 1 && !full) continue;
            f32x4 a; a.x = b1v; a.y = b1v; a.z = b1v; a.w = b1v;
#pragma unroll
            for (int ks = 0; ks < 4; ks++) a = mfma16(afr[mt][ks], bfr[ks], a);
#pragma unroll
            for (int j = 0; j < 4; j++) {
                const float g = gelu_fast(a[j]);
                s.H1[mt * 16 + lh * 4 + j][n] = f2bf(g);
                pb[mt][j] += g * w2cv;
            }
        }
    }
#pragma unroll
    for (int mt = 0; mt < 2; mt++) {
        if (mt == 1 && !full) continue;
#pragma unroll
        for (int j = 0; j < 4; j++) {
            float v = pb[mt][j];
            v += __shfl_xor(v, 1);
            v += __shfl_xor(v, 2);
            v += __shfl_xor(v, 4);
            v += __shfl_xor(v, 8);
            if (lr == 0) atomicAdd(&s.biasS[mt * 16 + lh * 4 + j], v);
        }
    }
    __syncthreads();   // H1 + biasS ready

    // ---- GEMM2 [32x128] = H1 @ W2T; bounce into hT as Wl[j][d] bf16 ----
#pragma unroll
    for (int mt = 0; mt < 2; mt++) {
        if (mt == 1 && !full) continue;
        short8v a2[8];
#pragma unroll
        for (int ks = 0; ks < 8; ks++)
            a2[ks] = *(const short8v*)&s.H1[mt * 16 + lr][ks * 32 + lh * 8];
#pragma unroll
        for (int nt = 0; nt < 2; nt++) {
            const int n = wv * 32 + nt * 16 + lr;
            short8v bf[8];
#pragma unroll
            for (int ks = 0; ks < 8; ks++)
                bf[ks] = *(const short8v*)(W2T + n * 256 + ks * 32 + lh * 8);
            const float b2v = b2[n];
            f32x4 a; a.x = b2v; a.y = b2v; a.z = b2v; a.w = b2v;
#pragma unroll
            for (int ks = 0; ks < 8; ks++) a = mfma16(a2[ks], bf[ks], a);
#pragma unroll
            for (int j = 0; j < 4; j++)
                s.hT[mt * 16 + lh * 4 + j][wv * 32 + nt * 16 + lr] = f2bf(a[j]);
        }
    }
    __syncthreads();   // Wl ready

    // ---- decode: C[64t x 32j] = Ubf @ Wl^T; scatter store + bias ----
    short8v bfr2[2][4];
#pragma unroll
    for (int nt = 0; nt < 2; nt++)
#pragma unroll
        for (int ks = 0; ks < 4; ks++)
            bfr2[nt][ks] = *(const short8v*)&s.hT[nt * 16 + lr][ks * 32 + lh * 8];

#pragma unroll
    for (int nt = 0; nt < 2; nt++) {
        f32x4 a; a.x = 0.f; a.y = 0.f; a.z = 0.f; a.w = 0.f;
#pragma unroll
        for (int ks = 0; ks < 4; ks++) a = mfma16(afr2[ks], bfr2[nt][ks], a);
        const int j = nt * 16 + lr;
        if (j < cc) {
            const int nid = order[bb * NN + s0 + base + j];
            const float bs = s.biasS[j] + b2last;
#pragma unroll
            for (int jr = 0; jr < 4; jr++)
                out[(size_t)(bb * 128 + t0 + wv * 16 + lh * 4 + jr) * NN + nid] =
                    a[jr] + bs;
        }
    }
}

extern "C" void kernel_launch(void* const* d_in, const int* in_sizes, int n_in,
                              void* d_out, int out_size, void* d_ws, size_t ws_size,
                              hipStream_t stream)
{
    const float* U              = (const float*)d_in[0];
    const int*   neuron_regions = (const int*)d_in[1];
    const int*   eids           = (const int*)d_in[2];
    const int*   r_map          = (const int*)d_in[3];
    const float* neuron_slot    = (const float*)d_in[4];
    const float* region_emb     = (const float*)d_in[5];
    const float* eid_emb        = (const float*)d_in[6];
    const float* ln_gamma       = (const float*)d_in[7];
    const float* ln_beta        = (const float*)d_in[8];
    const float* W1             = (const float*)d_in[9];
    const float* b1             = (const float*)d_in[10];
    const float* W2             = (const float*)d_in[11];
    const float* b2             = (const float*)d_in[12];

    char* ws = (char*)d_ws;
    unsigned short* W1T    = (unsigned short*)(ws);             // 64 KiB
    unsigned short* W2T    = (unsigned short*)(ws + 0x10000);   // 64 KiB
    float*          w2col  = (float*)(ws + 0x20000);            // 1 KiB
    int*            order  = (int*)(ws + 0x21000);              // 32 KiB
    int*            offs   = (int*)(ws + 0x29000);              // ~1 KiB
    int*            desc   = (int*)(ws + 0x2A000);              // 2 KiB
    int*            dcount = (int*)(ws + 0x2B000);              // 16 B
    float* outp = (float*)d_out;

    hipLaunchKernelGGL(prep_kernel, dim3(69), dim3(256), 0, stream,
                       W1, W2, r_map, neuron_regions, W1T, W2T, w2col,
                       order, offs, desc, dcount);
    hipLaunchKernelGGL(main_kernel, dim3(1024), dim3(256), 0, stream,
                       U, order, offs, desc, dcount, neuron_regions, eids,
                       neuron_slot, region_emb, eid_emb, ln_gamma, ln_beta,
                       b1, b2, W1T, W2T, w2col, outp);
}

// Round 14
// 40.353 us; speedup vs baseline: 2.2442x; 1.2992x over previous
//
#include <hip/hip_runtime.h>
#include <hip/hip_bf16.h>
#include <math.h>

#define DEV __device__ __forceinline__

typedef __attribute__((ext_vector_type(8))) short short8v;
typedef __attribute__((ext_vector_type(4))) float f32x4;

DEV float bf2f(unsigned short u) { return __uint_as_float(((unsigned)u) << 16); }
DEV unsigned short f2bf(float x) {
    unsigned u = __float_as_uint(x);
    return (unsigned short)((u + 0x7fffu + ((u >> 16) & 1u)) >> 16);
}
DEV unsigned pack2(float lo, float hi) {
    return ((unsigned)f2bf(hi) << 16) | (unsigned)f2bf(lo);
}
DEV f32x4 mfma16(short8v a, short8v b, f32x4 c) {
    return __builtin_amdgcn_mfma_f32_16x16x32_bf16(a, b, c, 0, 0, 0);
}

// Exact-GELU via Abramowitz-Stegun 7.1.26 erf (|err| <= 1.5e-7), ~16 VALU ops.
DEV float gelu_fast(float x) {
    const float z  = x * 0.70710678118654752f;
    const float az = fabsf(z);
    const float t  = __builtin_amdgcn_rcpf(fmaf(0.3275911f, az, 1.0f));
    float p = fmaf(t, 1.061405429f, -1.453152027f);
    p = fmaf(t, p, 1.421413741f);
    p = fmaf(t, p, -0.284496736f);
    p = fmaf(t, p, 0.254829592f);
    p = p * t;
    const float E = __builtin_amdgcn_exp2f(z * z * -1.4426950408889634f);
    const float erf_az = fmaf(-p, E, 1.0f);
    const float erf_z  = copysignf(erf_az, z);
    const float hx = 0.5f * x;
    return fmaf(hx, erf_z, hx);
}

#define NN 2048

// ==================================================================
// prep: blocks 0..31  W1[128][256] -> W1T bf16 [256][128]
//       blocks 32..63 W2[256][129] cols0..127 -> W2T bf16 [128][256]
//       block  64     w2col[256] = W2[:,128] (f32)
//       blocks 65..68 counting sort of neurons by local region (per b)
// ==================================================================
__global__ __launch_bounds__(256, 1) void prep_kernel(
    const float* __restrict__ W1, const float* __restrict__ W2,
    const int* __restrict__ r_map, const int* __restrict__ neuron_regions,
    unsigned short* __restrict__ W1T, unsigned short* __restrict__ W2T,
    float* __restrict__ w2col, int* __restrict__ order, int* __restrict__ offs)
{
    __shared__ __align__(16) float T[32][33];
    __shared__ int hist[65], starts[66], cursor[65];
    const int tid = threadIdx.x;
    const int bid = blockIdx.x;

    if (bid < 32) {
        const int tr = bid >> 3, tc = bid & 7;
#pragma unroll
        for (int p = 0; p < 4; p++) {
            const int i = p * 8 + (tid >> 5), j = tid & 31;
            T[i][j] = W1[(tr * 32 + i) * 256 + tc * 32 + j];
        }
        __syncthreads();
#pragma unroll
        for (int p = 0; p < 4; p++) {
            const int i = p * 8 + (tid >> 5), j = tid & 31;
            W1T[(tc * 32 + i) * 128 + tr * 32 + j] = f2bf(T[j][i]);
        }
    } else if (bid < 64) {
        const int bb = bid - 32, tr = bb >> 2, tc = bb & 3;
#pragma unroll
        for (int p = 0; p < 4; p++) {
            const int i = p * 8 + (tid >> 5), j = tid & 31;
            T[i][j] = W2[(tr * 32 + i) * 129 + tc * 32 + j];
        }
        __syncthreads();
#pragma unroll
        for (int p = 0; p < 4; p++) {
            const int i = p * 8 + (tid >> 5), j = tid & 31;
            W2T[(tc * 32 + i) * 256 + tr * 32 + j] = f2bf(T[j][i]);
        }
    } else if (bid == 64) {
        w2col[tid] = W2[tid * 129 + 128];
    } else {
        const int b = bid - 65;
        for (int i = tid; i < 65; i += 256) hist[i] = 0;
        __syncthreads();
        for (int n = tid; n < NN; n += 256) {
            int nr = min(max(neuron_regions[b * NN + n], 0), 127);
            int lr = r_map[nr];
            int bin = (lr < 0) ? 64 : min(lr, 63);
            atomicAdd(&hist[bin], 1);
        }
        __syncthreads();
        if (tid == 0) {
            int run = 0;
            for (int i = 0; i < 65; i++) { starts[i] = run; cursor[i] = run; run += hist[i]; }
            starts[65] = run;
        }
        __syncthreads();
        for (int i = tid; i < 66; i += 256) offs[b * 66 + i] = starts[i];
        for (int n = tid; n < NN; n += 256) {
            int nr = min(max(neuron_regions[b * NN + n], 0), 127);
            int lr = r_map[nr];
            int bin = (lr < 0) ? 64 : min(lr, 63);
            int pos = atomicAdd(&cursor[bin], 1);
            order[b * NN + pos] = n;
        }
    }
}

// ==================================================================
// p1: per-(b,n) hypernetwork via bf16 MFMA. 512 blocks x 16 rows.
// ==================================================================
__global__ __launch_bounds__(256, 1) void p1_kernel(
    const int* __restrict__ neuron_regions, const int* __restrict__ eids,
    const float* __restrict__ neuron_slot, const float* __restrict__ region_emb,
    const float* __restrict__ eid_emb, const float* __restrict__ ln_gamma,
    const float* __restrict__ ln_beta, const float* __restrict__ b1,
    const float* __restrict__ b2, const unsigned short* __restrict__ W1T,
    const unsigned short* __restrict__ W2T, const float* __restrict__ w2col,
    unsigned short* __restrict__ w_ws, float* __restrict__ bias_ws)
{
    __shared__ __align__(16) unsigned short hT[16][136];   // h bf16 (also out-bounce)
    __shared__ __align__(16) unsigned short H1[16][264];   // gelu(hW1+b1) bf16
    __shared__ float biasp[16];
    const int tid = threadIdx.x;
    const int row0 = blockIdx.x * 16;
    if (tid < 16) biasp[tid] = 0.f;

    // ---------- Stage A: e + LayerNorm -> hT ----------
    {
        const int rr = tid >> 4, q = tid & 15;    // 16 rows x 16 lanes
        const int row = row0 + rr;
        const int b = row >> 11, n = row & (NN - 1);
        int nr = min(max(neuron_regions[b * NN + n], 0), 127);
        int eid = min(max(eids[b], 0), 255);
        const float* ns = neuron_slot + n * 128 + q * 8;
        const float* re = region_emb + nr * 128 + q * 8;
        const float* ee = eid_emb + eid * 128 + q * 8;
        float e[8];
        {
            float4 a0 = *(const float4*)ns, a1 = *(const float4*)(ns + 4);
            float4 c0 = *(const float4*)re, c1 = *(const float4*)(re + 4);
            float4 d0 = *(const float4*)ee, d1 = *(const float4*)(ee + 4);
            e[0] = a0.x + c0.x + d0.x; e[1] = a0.y + c0.y + d0.y;
            e[2] = a0.z + c0.z + d0.z; e[3] = a0.w + c0.w + d0.w;
            e[4] = a1.x + c1.x + d1.x; e[5] = a1.y + c1.y + d1.y;
            e[6] = a1.z + c1.z + d1.z; e[7] = a1.w + c1.w + d1.w;
        }
        float s = 0.f, s2 = 0.f;
#pragma unroll
        for (int i = 0; i < 8; i++) { s += e[i]; s2 += e[i] * e[i]; }
        s += __shfl_xor(s, 1);  s2 += __shfl_xor(s2, 1);
        s += __shfl_xor(s, 2);  s2 += __shfl_xor(s2, 2);
        s += __shfl_xor(s, 4);  s2 += __shfl_xor(s2, 4);
        s += __shfl_xor(s, 8);  s2 += __shfl_xor(s2, 8);
        const float mu = s * (1.f / 128.f);
        const float var = s2 * (1.f / 128.f) - mu * mu;
        const float rstd = rsqrtf(var + 1e-5f);
        float4 g0 = *(const float4*)(ln_gamma + q * 8), g1 = *(const float4*)(ln_gamma + q * 8 + 4);
        float4 t0 = *(const float4*)(ln_beta + q * 8),  t1 = *(const float4*)(ln_beta + q * 8 + 4);
        float gm[8] = {g0.x, g0.y, g0.z, g0.w, g1.x, g1.y, g1.z, g1.w};
        float bt[8] = {t0.x, t0.y, t0.z, t0.w, t1.x, t1.y, t1.z, t1.w};
        float h[8];
#pragma unroll
        for (int i = 0; i < 8; i++) h[i] = (e[i] - mu) * rstd * gm[i] + bt[i];
        uint4 pk;
        pk.x = pack2(h[0], h[1]); pk.y = pack2(h[2], h[3]);
        pk.z = pack2(h[4], h[5]); pk.w = pack2(h[6], h[7]);
        *(uint4*)&hT[rr][q * 8] = pk;
    }
    __syncthreads();

    const int wv = tid >> 6, l = tid & 63;
    const int lr = l & 15, lh = l >> 4;

    // ---------- GEMM1: C1[16x256] = h @ W1  (wave wv owns cols wv*64..+63) ----------
    short8v afr[4];
#pragma unroll
    for (int ks = 0; ks < 4; ks++)
        afr[ks] = *(const short8v*)&hT[lr][ks * 32 + lh * 8];

    f32x4 acc1[4];
    short8v bfr[4][4];
    float w2c[4];
#pragma unroll
    for (int nt = 0; nt < 4; nt++) {
        const int n = wv * 64 + nt * 16 + lr;
#pragma unroll
        for (int ks = 0; ks < 4; ks++)
            bfr[nt][ks] = *(const short8v*)(W1T + n * 128 + ks * 32 + lh * 8);
        const float bb = b1[n];
        acc1[nt].x = bb; acc1[nt].y = bb; acc1[nt].z = bb; acc1[nt].w = bb;
        w2c[nt] = w2col[n];
    }
#pragma unroll
    for (int nt = 0; nt < 4; nt++)
#pragma unroll
        for (int ks = 0; ks < 4; ks++)
            acc1[nt] = mfma16(afr[ks], bfr[nt][ks], acc1[nt]);

    // ---------- GELU -> H1 (bf16) + bias-column partials ----------
    float pb[4] = {0.f, 0.f, 0.f, 0.f};
#pragma unroll
    for (int nt = 0; nt < 4; nt++) {
        const int n = wv * 64 + nt * 16 + lr;
#pragma unroll
        for (int j = 0; j < 4; j++) {
            const float g = gelu_fast(acc1[nt][j]);
            H1[lh * 4 + j][n] = f2bf(g);
            pb[j] += g * w2c[nt];
        }
    }
#pragma unroll
    for (int j = 0; j < 4; j++) {
        pb[j] += __shfl_xor(pb[j], 1);
        pb[j] += __shfl_xor(pb[j], 2);
        pb[j] += __shfl_xor(pb[j], 4);
        pb[j] += __shfl_xor(pb[j], 8);
    }
    if (lr == 0) {
#pragma unroll
        for (int j = 0; j < 4; j++) atomicAdd(&biasp[lh * 4 + j], pb[j]);
    }
    __syncthreads();

    if (tid < 16) bias_ws[row0 + tid] = biasp[tid] + b2[128];

    // ---------- GEMM2: C2[16x128] = H1 @ W2  (wave wv owns cols wv*32..+31) ----------
    short8v a2[8];
#pragma unroll
    for (int ks = 0; ks < 8; ks++)
        a2[ks] = *(const short8v*)&H1[lr][ks * 32 + lh * 8];

    f32x4 acc2[2];
    short8v b2f[2][8];
#pragma unroll
    for (int nt = 0; nt < 2; nt++) {
        const int n = wv * 32 + nt * 16 + lr;
#pragma unroll
        for (int ks = 0; ks < 8; ks++)
            b2f[nt][ks] = *(const short8v*)(W2T + n * 256 + ks * 32 + lh * 8);
        const float bb = b2[n];
        acc2[nt].x = bb; acc2[nt].y = bb; acc2[nt].z = bb; acc2[nt].w = bb;
    }
#pragma unroll
    for (int nt = 0; nt < 2; nt++)
#pragma unroll
        for (int ks = 0; ks < 8; ks++)
            acc2[nt] = mfma16(a2[ks], b2f[nt][ks], acc2[nt]);

    // ---------- bounce C2 through LDS (reuse hT), coalesced store ----------
#pragma unroll
    for (int nt = 0; nt < 2; nt++) {
        const int n = wv * 32 + nt * 16 + lr;
#pragma unroll
        for (int j = 0; j < 4; j++)
            hT[lh * 4 + j][n] = f2bf(acc2[nt][j]);
    }
    __syncthreads();
    {
        const int r = tid >> 4, c = tid & 15;
        uint4 v = *(const uint4*)&hT[r][c * 8];
        *(uint4*)(w_ws + (row0 + r) * 128 + c * 8) = v;
    }
}

// ==================================================================
// p2: blocks 0..255 = (b, region-slot) gather-GEMM; 256..259 dead-zero.
// ==================================================================
__global__ __launch_bounds__(256, 1) void p2_kernel(
    const float* __restrict__ U, const int* __restrict__ order,
    const int* __restrict__ offs, const unsigned short* __restrict__ w_ws,
    const float* __restrict__ bias_ws, float* __restrict__ out)
{
    __shared__ __align__(16) unsigned short Ubf[128][136];
    __shared__ __align__(16) unsigned short Bt[32][136];
    __shared__ int nidS[32];
    __shared__ float biasS[32];
    const int tid = threadIdx.x;
    const int bid = blockIdx.x;

    if (bid >= 256) {   // dead neurons -> zeros (no-op when none)
        const int b = bid - 256;
        const int s64 = offs[b * 66 + 64], s65 = offs[b * 66 + 65];
        const int cnt = s65 - s64;
        for (int idx = tid; idx < cnt * 128; idx += 256) {
            const int j = idx >> 7, t = idx & 127;
            const int n = order[b * NN + s64 + j];
            out[(b * 128 + t) * NN + n] = 0.f;
        }
        return;
    }

    const int b = bid >> 6, slot = bid & 63;
    const int s0 = offs[b * 66 + slot], s1 = offs[b * 66 + slot + 1];
    const int cnt = s1 - s0;
    if (cnt <= 0) return;

    // stage U[b, :, slot, :] as bf16
    {
        const int t = tid >> 1, half = tid & 1;
        const float* src = U + ((size_t)((b * 128 + t) * 64 + slot)) * 128 + half * 64;
        unsigned short* dst = &Ubf[t][half * 64];
#pragma unroll
        for (int j = 0; j < 16; j++) {
            float4 v = ((const float4*)src)[j];
            ((uint2*)dst)[j] = make_uint2(pack2(v.x, v.y), pack2(v.z, v.w));
        }
    }
    __syncthreads();

    const int wv = tid >> 6, l = tid & 63;
    const int lr = l & 15, lh = l >> 4;

    short8v afr[2][4];
#pragma unroll
    for (int mt = 0; mt < 2; mt++)
#pragma unroll
        for (int ks = 0; ks < 4; ks++)
            afr[mt][ks] = *(const short8v*)&Ubf[wv * 32 + mt * 16 + lr][ks * 32 + lh * 8];

    const int nChunks = (cnt + 31) >> 5;
    for (int c = 0; c < nChunks; c++) {
        const int base = s0 + c * 32;
        const int cc = min(cnt - c * 32, 32);
        __syncthreads();   // previous chunk's Bt/nidS reads complete
        if (tid < 32) {
            const int nid = (tid < cc) ? order[b * NN + base + tid] : -1;
            nidS[tid] = nid;
            biasS[tid] = (nid >= 0) ? bias_ws[b * NN + nid] : 0.f;
        }
        {
            const int jj = tid >> 3, q = tid & 7;
            const int nid = (jj < cc) ? order[b * NN + base + jj] : -1;
            unsigned short* dst = &Bt[jj][q * 16];
            if (nid >= 0) {
                const uint4* src = (const uint4*)(w_ws + ((size_t)(b * NN + nid)) * 128 + q * 16);
                ((uint4*)dst)[0] = src[0];
                ((uint4*)dst)[1] = src[1];
            } else {
                ((uint4*)dst)[0] = make_uint4(0, 0, 0, 0);
                ((uint4*)dst)[1] = make_uint4(0, 0, 0, 0);
            }
        }
        __syncthreads();

        f32x4 acc[2][2];
#pragma unroll
        for (int mt = 0; mt < 2; mt++)
#pragma unroll
            for (int nt = 0; nt < 2; nt++) {
                acc[mt][nt].x = 0.f; acc[mt][nt].y = 0.f;
                acc[mt][nt].z = 0.f; acc[mt][nt].w = 0.f;
            }
        short8v bfr[2][4];
#pragma unroll
        for (int nt = 0; nt < 2; nt++)
#pragma unroll
            for (int ks = 0; ks < 4; ks++)
                bfr[nt][ks] = *(const short8v*)&Bt[nt * 16 + lr][ks * 32 + lh * 8];
#pragma unroll
        for (int mt = 0; mt < 2; mt++)
#pragma unroll
            for (int nt = 0; nt < 2; nt++)
#pragma unroll
                for (int ks = 0; ks < 4; ks++)
                    acc[mt][nt] = mfma16(afr[mt][ks], bfr[nt][ks], acc[mt][nt]);

#pragma unroll
        for (int nt = 0; nt < 2; nt++) {
            const int j = nt * 16 + lr;
            const int nid = nidS[j];
            if (nid >= 0) {
                const float bs = biasS[j];
#pragma unroll
                for (int mt = 0; mt < 2; mt++) {
                    const int tt = wv * 32 + mt * 16 + lh * 4;
#pragma unroll
                    for (int jr = 0; jr < 4; jr++)
                        out[(b * 128 + tt + jr) * NN + nid] = acc[mt][nt][jr] + bs;
                }
            }
        }
    }
}

extern "C" void kernel_launch(void* const* d_in, const int* in_sizes, int n_in,
                              void* d_out, int out_size, void* d_ws, size_t ws_size,
                              hipStream_t stream)
{
    const float* U              = (const float*)d_in[0];
    const int*   neuron_regions = (const int*)d_in[1];
    const int*   eids           = (const int*)d_in[2];
    const int*   r_map          = (const int*)d_in[3];
    const float* neuron_slot    = (const float*)d_in[4];
    const float* region_emb     = (const float*)d_in[5];
    const float* eid_emb        = (const float*)d_in[6];
    const float* ln_gamma       = (const float*)d_in[7];
    const float* ln_beta        = (const float*)d_in[8];
    const float* W1             = (const float*)d_in[9];
    const float* b1             = (const float*)d_in[10];
    const float* W2             = (const float*)d_in[11];
    const float* b2             = (const float*)d_in[12];

    char* ws = (char*)d_ws;
    unsigned short* w_ws  = (unsigned short*)(ws);                    // 2 MB
    float*          bias_ws = (float*)(ws + 2097152);                 // 32 KB
    unsigned short* W1T   = (unsigned short*)(ws + 2129920);          // 64 KB
    unsigned short* W2T   = (unsigned short*)(ws + 2195456);          // 64 KB
    float*          w2col = (float*)(ws + 2260992);                   // 1 KB
    int*            order = (int*)(ws + 2262016);                     // 32 KB
    int*            offs  = (int*)(ws + 2294784);                     // ~1 KB
    float* outp = (float*)d_out;

    hipLaunchKernelGGL(prep_kernel, dim3(69), dim3(256), 0, stream,
                       W1, W2, r_map, neuron_regions, W1T, W2T, w2col, order, offs);
    hipLaunchKernelGGL(p1_kernel, dim3(512), dim3(256), 0, stream,
                       neuron_regions, eids, neuron_slot, region_emb, eid_emb,
                       ln_gamma, ln_beta, b1, b2, W1T, W2T, w2col, w_ws, bias_ws);
    hipLaunchKernelGGL(p2_kernel, dim3(260), dim3(256), 0, stream,
                       U, order, offs, w_ws, bias_ws, outp);
}